// Round 3
// baseline (1485.477 us; speedup 1.0000x reference)
//
#include <hip/hip_runtime.h>
#include <hip/hip_bf16.h>
#include <math.h>

#define NPTS 100000
#define PAD_ROWS 100096   // 782 * 128
#define DIM 512
#define GRP 4
#define GD 128
#define K_NBR 16
#define EPS 1e-5f

using bf16x8 = __attribute__((ext_vector_type(8))) short;
using f32x4  = __attribute__((ext_vector_type(4))) float;
using short4v = __attribute__((ext_vector_type(4))) short;

__device__ inline float bf2f(short s) {
    unsigned u = ((unsigned)(unsigned short)s) << 16;
    union { unsigned u; float f; } c; c.u = u; return c.f;
}
__device__ inline short f2bf(float f) {
    union { float f; unsigned u; } c; c.f = f;
    unsigned u = c.u;
    unsigned r = (u + 0x7fffu + ((u >> 16) & 1u)) >> 16;
    return (short)r;
}

__device__ __forceinline__ void gload_lds16(short* lds, const short* g) {
    __builtin_amdgcn_global_load_lds(
        (const __attribute__((address_space(1))) unsigned int*)g,
        (__attribute__((address_space(3))) unsigned int*)lds, 16, 0, 0);
}

// ---------------- weight convert f32 -> bf16 ----------------
__global__ void cvt_kernel(const float* __restrict__ src, short* __restrict__ dst, int n) {
    int i = blockIdx.x * blockDim.x + threadIdx.x;
    int stride = gridDim.x * blockDim.x;
    for (; i < n; i += stride) dst[i] = f2bf(src[i]);
}

// ---------------- LayerNorm (f32 in -> bf16 out) ----------------
__global__ void ln_kernel(const float* __restrict__ in, const float* __restrict__ g,
                          const float* __restrict__ b, short* __restrict__ out) {
    int row = blockIdx.x;
    int tid = threadIdx.x; // 128 threads, 4 elems each
    if (row >= NPTS) {
        short4v z; z[0] = 0; z[1] = 0; z[2] = 0; z[3] = 0;
        *(short4v*)(out + (size_t)row * DIM + tid * 4) = z;
        return;
    }
    const float4 x = *(const float4*)(in + (size_t)row * DIM + tid * 4);
    float s  = x.x + x.y + x.z + x.w;
    float sq = x.x * x.x + x.y * x.y + x.z * x.z + x.w * x.w;
    for (int m = 1; m < 64; m <<= 1) {
        s  += __shfl_xor(s, m);
        sq += __shfl_xor(sq, m);
    }
    __shared__ float ss[2], ssq[2];
    int wv = tid >> 6;
    if ((tid & 63) == 0) { ss[wv] = s; ssq[wv] = sq; }
    __syncthreads();
    s = ss[0] + ss[1]; sq = ssq[0] + ssq[1];
    float mu = s * (1.0f / DIM);
    float var = sq * (1.0f / DIM) - mu * mu;
    float rstd = rsqrtf(var + EPS);
    const float4 gg = *(const float4*)(g + tid * 4);
    const float4 bb = *(const float4*)(b + tid * 4);
    short4v o;
    o[0] = f2bf((x.x - mu) * rstd * gg.x + bb.x);
    o[1] = f2bf((x.y - mu) * rstd * gg.y + bb.y);
    o[2] = f2bf((x.z - mu) * rstd * gg.z + bb.z);
    o[3] = f2bf((x.w - mu) * rstd * gg.w + bb.w);
    *(short4v*)(out + (size_t)row * DIM + tid * 4) = o;
}

// ---------------- shared 128x128 GEMM core (BK=32, 4 waves 2x2, m97 structure) --------
template<int NK>
__device__ __forceinline__ void gemm_tile(
        const short* __restrict__ aBase, int as_,   // &A[rowbase][k0], row stride
        const short* __restrict__ bBase, int bs_,   // &B[colbase][k0], row stride
        short* As, short* Bs, f32x4 (&acc)[4][4]) {
    int tid = threadIdx.x;
    int lane = tid & 63, wave = tid >> 6;
    int wr = wave >> 1, wc = wave & 1;
    int r = lane & 15, ks = lane >> 4;
    int ldRow = tid >> 2;            // 0..63
    int ldCol = (tid & 3) * 8;       // element col within BK=32
    for (int kt = 0; kt < NK; ++kt) {
        __syncthreads();
        const short* aS = aBase + kt * 32;
        const short* bS = bBase + kt * 32;
        gload_lds16(As + (ldRow)      * 32 + ldCol, aS + (size_t)(ldRow)      * as_ + ldCol);
        gload_lds16(As + (ldRow + 64) * 32 + ldCol, aS + (size_t)(ldRow + 64) * as_ + ldCol);
        gload_lds16(Bs + (ldRow)      * 32 + ldCol, bS + (size_t)(ldRow)      * bs_ + ldCol);
        gload_lds16(Bs + (ldRow + 64) * 32 + ldCol, bS + (size_t)(ldRow + 64) * bs_ + ldCol);
        __syncthreads();
        bf16x8 a[4];
        #pragma unroll
        for (int m = 0; m < 4; ++m)
            a[m] = *(const bf16x8*)(As + (wr * 64 + m * 16 + r) * 32 + ks * 8);
        #pragma unroll
        for (int n = 0; n < 4; ++n) {
            bf16x8 b = *(const bf16x8*)(Bs + (wc * 64 + n * 16 + r) * 32 + ks * 8);
            #pragma unroll
            for (int m = 0; m < 4; ++m)
                acc[m][n] = __builtin_amdgcn_mfma_f32_16x16x32_bf16(a[m], b, acc[m][n], 0, 0, 0);
        }
    }
}

// ---------------- fused grouped QKV: per block (rowblock, group), loop q/k/v ----------
__global__ __launch_bounds__(256) void qkv_kernel(
        const short* __restrict__ x,
        const short* __restrict__ wq, const short* __restrict__ wk, const short* __restrict__ wv,
        short* __restrict__ q, short* __restrict__ k, short* __restrict__ v) {
    __shared__ short As[128 * 32], Bs[128 * 32];
    int nwg = gridDim.x;             // 782*4 = 3128, %8==0
    int bid = blockIdx.x;
    int tile = (bid & 7) * (nwg >> 3) + (bid >> 3);
    int rb = tile >> 2, g = tile & 3;
    int rowbase = rb * 128;
    int tid = threadIdx.x;
    int lane = tid & 63, wave = tid >> 6;
    int wr = wave >> 1, wc = wave & 1;
    int r = lane & 15, ks = lane >> 4;
    const short* Ws[3] = {wq, wk, wv};
    short* Os[3] = {q, k, v};
    #pragma unroll
    for (int t = 0; t < 3; ++t) {
        f32x4 acc[4][4];
        #pragma unroll
        for (int m = 0; m < 4; ++m)
            #pragma unroll
            for (int n = 0; n < 4; ++n)
                #pragma unroll
                for (int e = 0; e < 4; ++e) acc[m][n][e] = 0.0f;
        gemm_tile<4>(x + (size_t)rowbase * DIM + g * GD, DIM,
                     Ws[t] + g * GD * GD, GD, As, Bs, acc);
        short* O = Os[t];
        #pragma unroll
        for (int m = 0; m < 4; ++m)
            #pragma unroll
            for (int n = 0; n < 4; ++n)
                #pragma unroll
                for (int rr = 0; rr < 4; ++rr) {
                    int orow = rowbase + wr * 64 + m * 16 + ks * 4 + rr;
                    int ocol = g * GD + wc * 64 + n * 16 + r;
                    O[(size_t)orow * DIM + ocol] = f2bf(acc[m][n][rr]);
                }
    }
}

// ---------------- attention: one wave per (point, group), 4 nbr-slots x 16 dim-slots --
__global__ __launch_bounds__(256) void attn_kernel(
        const short* __restrict__ q, const short* __restrict__ kk, const short* __restrict__ vv,
        const int* __restrict__ nbrs, short* __restrict__ attn) {
    int n = blockIdx.x;
    __shared__ int nb[K_NBR];
    int tid = threadIdx.x;
    if (tid < K_NBR) nb[tid] = nbrs[(size_t)n * K_NBR + tid];
    __syncthreads();
    int g = tid >> 6, lane = tid & 63;
    int s = lane >> 4, t = lane & 15;
    const float scale = 0.08838834764831845f; // 1/sqrt(128)
    size_t gbase = (size_t)n * DIM + g * GD + t * 8;
    bf16x8 qf = *(const bf16x8*)(q + gbase);
    float qv[8];
    #pragma unroll
    for (int e = 0; e < 8; ++e) qv[e] = bf2f(qf[e]);
    // ---- QK^T: pass p covers neighbors {p*4+s} ----
    float sc[4];
    #pragma unroll
    for (int p = 0; p < 4; ++p) {
        int j = p * 4 + s;
        bf16x8 kf = *(const bf16x8*)(kk + (size_t)nb[j] * DIM + g * GD + t * 8);
        float d = 0.0f;
        #pragma unroll
        for (int e = 0; e < 8; ++e) d += qv[e] * bf2f(kf[e]);
        d += __shfl_xor(d, 1);
        d += __shfl_xor(d, 2);
        d += __shfl_xor(d, 4);
        d += __shfl_xor(d, 8);
        sc[p] = d * scale;
    }
    // ---- softmax over 16 neighbors (4 local + cross-slot) ----
    float mx = fmaxf(fmaxf(sc[0], sc[1]), fmaxf(sc[2], sc[3]));
    mx = fmaxf(mx, __shfl_xor(mx, 16));
    mx = fmaxf(mx, __shfl_xor(mx, 32));
    float ew[4]; float ssum = 0.0f;
    #pragma unroll
    for (int p = 0; p < 4; ++p) { ew[p] = __expf(sc[p] - mx); ssum += ew[p]; }
    ssum += __shfl_xor(ssum, 16);
    ssum += __shfl_xor(ssum, 32);
    // ---- PV: accumulate unnormalized, normalize once ----
    float acc[8];
    #pragma unroll
    for (int d0 = 0; d0 < 8; ++d0) acc[d0] = 0.0f;
    #pragma unroll
    for (int p = 0; p < 4; ++p) {
        int j = p * 4 + s;
        bf16x8 vf = *(const bf16x8*)(vv + (size_t)nb[j] * DIM + g * GD + t * 8);
        #pragma unroll
        for (int d0 = 0; d0 < 8; ++d0) acc[d0] += ew[p] * bf2f(vf[d0]);
    }
    #pragma unroll
    for (int d0 = 0; d0 < 8; ++d0) {
        acc[d0] += __shfl_xor(acc[d0], 16);
        acc[d0] += __shfl_xor(acc[d0], 32);
    }
    if (s == 0) {
        float inv = 1.0f / ssum;
        bf16x8 o;
        #pragma unroll
        for (int d0 = 0; d0 < 8; ++d0) o[d0] = f2bf(acc[d0] * inv);
        *(bf16x8*)(attn + gbase) = o;
    }
}

// ---------------- out = attn @ Wo.T + bo + features (residual) -> f32 d_out ----------
__global__ __launch_bounds__(256) void outproj_kernel(
        const short* __restrict__ attn, const short* __restrict__ wo,
        const float* __restrict__ bo, const float* __restrict__ features,
        float* __restrict__ out) {
    __shared__ short As[128 * 32], Bs[128 * 32];
    int nwg = gridDim.x;             // 782*4
    int bid = blockIdx.x;
    int tile = (bid & 7) * (nwg >> 3) + (bid >> 3);
    int rb = tile >> 2, cb = tile & 3;
    int rowbase = rb * 128, colbase = cb * 128;
    int tid = threadIdx.x;
    int lane = tid & 63, wave = tid >> 6;
    int wr = wave >> 1, wc = wave & 1;
    int r = lane & 15, ks = lane >> 4;
    f32x4 acc[4][4];
    #pragma unroll
    for (int m = 0; m < 4; ++m)
        #pragma unroll
        for (int n = 0; n < 4; ++n)
            #pragma unroll
            for (int e = 0; e < 4; ++e) acc[m][n][e] = 0.0f;
    gemm_tile<16>(attn + (size_t)rowbase * DIM, DIM,
                  wo + (size_t)colbase * DIM, DIM, As, Bs, acc);
    #pragma unroll
    for (int m = 0; m < 4; ++m)
        #pragma unroll
        for (int n = 0; n < 4; ++n)
            #pragma unroll
            for (int rr = 0; rr < 4; ++rr) {
                int orow = rowbase + wr * 64 + m * 16 + ks * 4 + rr;
                int ocol = colbase + wc * 64 + n * 16 + r;
                if (orow < NPTS) {
                    out[(size_t)orow * DIM + ocol] =
                        acc[m][n][rr] + bo[ocol] + features[(size_t)orow * DIM + ocol];
                }
            }
}

// ---------------- FFN1: h = gelu(y @ W1.T + b1), bf16 out, N=1024 --------------------
__global__ __launch_bounds__(256) void ffn1_kernel(
        const short* __restrict__ y, const short* __restrict__ w1,
        const float* __restrict__ b1, short* __restrict__ h) {
    __shared__ short As[128 * 32], Bs[128 * 32];
    int nwg = gridDim.x;             // 782*8
    int bid = blockIdx.x;
    int tile = (bid & 7) * (nwg >> 3) + (bid >> 3);
    int rb = tile >> 3, cb = tile & 7;
    int rowbase = rb * 128, colbase = cb * 128;
    int tid = threadIdx.x;
    int lane = tid & 63, wave = tid >> 6;
    int wr = wave >> 1, wc = wave & 1;
    int r = lane & 15, ks = lane >> 4;
    f32x4 acc[4][4];
    #pragma unroll
    for (int m = 0; m < 4; ++m)
        #pragma unroll
        for (int n = 0; n < 4; ++n)
            #pragma unroll
            for (int e = 0; e < 4; ++e) acc[m][n][e] = 0.0f;
    gemm_tile<16>(y + (size_t)rowbase * DIM, DIM,
                  w1 + (size_t)colbase * DIM, DIM, As, Bs, acc);
    #pragma unroll
    for (int m = 0; m < 4; ++m)
        #pragma unroll
        for (int n = 0; n < 4; ++n)
            #pragma unroll
            for (int rr = 0; rr < 4; ++rr) {
                int orow = rowbase + wr * 64 + m * 16 + ks * 4 + rr;
                int ocol = colbase + wc * 64 + n * 16 + r;
                float xv = acc[m][n][rr] + b1[ocol];
                float gl = 0.5f * xv * (1.0f + erff(xv * 0.70710678118654752f));
                h[(size_t)orow * (2 * DIM) + ocol] = f2bf(gl);
            }
}

// ---------------- FFN2: d_out = h @ W2.T + b2 + d_out(res2), K=1024 ------------------
__global__ __launch_bounds__(256) void ffn2_kernel(
        const short* __restrict__ h, const short* __restrict__ w2,
        const float* __restrict__ b2, float* __restrict__ out) {
    __shared__ short As[128 * 32], Bs[128 * 32];
    int nwg = gridDim.x;             // 782*4
    int bid = blockIdx.x;
    int tile = (bid & 7) * (nwg >> 3) + (bid >> 3);
    int rb = tile >> 2, cb = tile & 3;
    int rowbase = rb * 128, colbase = cb * 128;
    int tid = threadIdx.x;
    int lane = tid & 63, wave = tid >> 6;
    int wr = wave >> 1, wc = wave & 1;
    int r = lane & 15, ks = lane >> 4;
    f32x4 acc[4][4];
    #pragma unroll
    for (int m = 0; m < 4; ++m)
        #pragma unroll
        for (int n = 0; n < 4; ++n)
            #pragma unroll
            for (int e = 0; e < 4; ++e) acc[m][n][e] = 0.0f;
    gemm_tile<32>(h + (size_t)rowbase * (2 * DIM), 2 * DIM,
                  w2 + (size_t)colbase * (2 * DIM), 2 * DIM, As, Bs, acc);
    #pragma unroll
    for (int m = 0; m < 4; ++m)
        #pragma unroll
        for (int n = 0; n < 4; ++n)
            #pragma unroll
            for (int rr = 0; rr < 4; ++rr) {
                int orow = rowbase + wr * 64 + m * 16 + ks * 4 + rr;
                int ocol = colbase + wc * 64 + n * 16 + r;
                if (orow < NPTS) {
                    size_t idx = (size_t)orow * DIM + ocol;
                    out[idx] = acc[m][n][rr] + b2[ocol] + out[idx];
                }
            }
}

extern "C" void kernel_launch(void* const* d_in, const int* in_sizes, int n_in,
                              void* d_out, int out_size, void* d_ws, size_t ws_size,
                              hipStream_t stream) {
    const float* features = (const float*)d_in[0];
    const int*   neighbors = (const int*)d_in[2];
    const float* Wq = (const float*)d_in[3];
    const float* Wk = (const float*)d_in[4];
    const float* Wv = (const float*)d_in[5];
    const float* Wo = (const float*)d_in[6];
    const float* bo = (const float*)d_in[7];
    const float* ln1_g = (const float*)d_in[8];
    const float* ln1_b = (const float*)d_in[9];
    const float* ln2_g = (const float*)d_in[10];
    const float* ln2_b = (const float*)d_in[11];
    const float* W1 = (const float*)d_in[12];
    const float* b1 = (const float*)d_in[13];
    const float* W2 = (const float*)d_in[14];
    const float* b2 = (const float*)d_in[15];
    float* out = (float*)d_out;

    size_t slotElems = (size_t)PAD_ROWS * DIM;
    short* s0 = (short*)d_ws;            // x -> attn
    short* s1 = s0 + slotElems;          // q -> y(ln2)
    short* s2 = s1 + slotElems;          // k -> h (low half)
    short* s3 = s2 + slotElems;          // v -> h (high half)
    short* wq_b = s3 + slotElems;
    short* wk_b = wq_b + GRP * GD * GD;
    short* wv_b = wk_b + GRP * GD * GD;
    short* wo_b = wv_b + GRP * GD * GD;
    short* w1_b = wo_b + DIM * DIM;
    short* w2_b = w1_b + 2 * DIM * DIM;

    cvt_kernel<<<128, 256, 0, stream>>>(Wq, wq_b, GRP * GD * GD);
    cvt_kernel<<<128, 256, 0, stream>>>(Wk, wk_b, GRP * GD * GD);
    cvt_kernel<<<128, 256, 0, stream>>>(Wv, wv_b, GRP * GD * GD);
    cvt_kernel<<<256, 256, 0, stream>>>(Wo, wo_b, DIM * DIM);
    cvt_kernel<<<256, 256, 0, stream>>>(W1, w1_b, 2 * DIM * DIM);
    cvt_kernel<<<256, 256, 0, stream>>>(W2, w2_b, 2 * DIM * DIM);

    // LN1: features -> x (bf16), zero-padded rows
    ln_kernel<<<PAD_ROWS, 128, 0, stream>>>(features, ln1_g, ln1_b, s0);

    // grouped QKV (fused q/k/v loop per block)
    qkv_kernel<<<(PAD_ROWS / 128) * 4, 256, 0, stream>>>(s0, wq_b, wk_b, wv_b, s1, s2, s3);

    // attention -> attn in s0
    attn_kernel<<<NPTS, 256, 0, stream>>>(s1, s2, s3, neighbors, s0);

    // out = attn @ Wo.T + bo + features  (f32, in d_out)
    outproj_kernel<<<(PAD_ROWS / 128) * 4, 256, 0, stream>>>(s0, wo_b, bo, features, out);

    // LN2: d_out -> y (bf16) in s1
    ln_kernel<<<PAD_ROWS, 128, 0, stream>>>(out, ln2_g, ln2_b, s1);

    // FFN1: h = gelu(y @ W1.T + b1) -> s2:s3 (P x 1024 bf16)
    ffn1_kernel<<<(PAD_ROWS / 128) * 8, 256, 0, stream>>>(s1, w1_b, b1, s2);

    // FFN2: d_out = h @ W2.T + b2 + d_out
    ffn2_kernel<<<(PAD_ROWS / 128) * 4, 256, 0, stream>>>(s2, w2_b, b2, out);
}

// Round 4
// 1457.418 us; speedup vs baseline: 1.0193x; 1.0193x over previous
//
#include <hip/hip_runtime.h>
#include <hip/hip_bf16.h>
#include <math.h>

#define NPTS 100000
#define PAD_ROWS 100096   // 782 * 128
#define DIM 512
#define GRP 4
#define GD 128
#define K_NBR 16
#define EPS 1e-5f

using bf16x8 = __attribute__((ext_vector_type(8))) short;
using f32x4  = __attribute__((ext_vector_type(4))) float;
using short4v = __attribute__((ext_vector_type(4))) short;

__device__ inline float bf2f(short s) {
    unsigned u = ((unsigned)(unsigned short)s) << 16;
    union { unsigned u; float f; } c; c.u = u; return c.f;
}
__device__ inline short f2bf(float f) {
    union { float f; unsigned u; } c; c.f = f;
    unsigned u = c.u;
    unsigned r = (u + 0x7fffu + ((u >> 16) & 1u)) >> 16;
    return (short)r;
}

__device__ __forceinline__ void gload_lds16(short* lds, const short* g) {
    __builtin_amdgcn_global_load_lds(
        (const __attribute__((address_space(1))) unsigned int*)g,
        (__attribute__((address_space(3))) unsigned int*)lds, 16, 0, 0);
}

// ---------------- weight convert f32 -> bf16 ----------------
__global__ void cvt_kernel(const float* __restrict__ src, short* __restrict__ dst, int n) {
    int i = blockIdx.x * blockDim.x + threadIdx.x;
    int stride = gridDim.x * blockDim.x;
    for (; i < n; i += stride) dst[i] = f2bf(src[i]);
}

// ---------------- LayerNorm (f32 in -> bf16 out) ----------------
__global__ void ln_kernel(const float* __restrict__ in, const float* __restrict__ g,
                          const float* __restrict__ b, short* __restrict__ out) {
    int row = blockIdx.x;
    int tid = threadIdx.x; // 128 threads, 4 elems each
    if (row >= NPTS) {
        short4v z; z[0] = 0; z[1] = 0; z[2] = 0; z[3] = 0;
        *(short4v*)(out + (size_t)row * DIM + tid * 4) = z;
        return;
    }
    const float4 x = *(const float4*)(in + (size_t)row * DIM + tid * 4);
    float s  = x.x + x.y + x.z + x.w;
    float sq = x.x * x.x + x.y * x.y + x.z * x.z + x.w * x.w;
    for (int m = 1; m < 64; m <<= 1) {
        s  += __shfl_xor(s, m);
        sq += __shfl_xor(sq, m);
    }
    __shared__ float ss[2], ssq[2];
    int wv = tid >> 6;
    if ((tid & 63) == 0) { ss[wv] = s; ssq[wv] = sq; }
    __syncthreads();
    s = ss[0] + ss[1]; sq = ssq[0] + ssq[1];
    float mu = s * (1.0f / DIM);
    float var = sq * (1.0f / DIM) - mu * mu;
    float rstd = rsqrtf(var + EPS);
    const float4 gg = *(const float4*)(g + tid * 4);
    const float4 bb = *(const float4*)(b + tid * 4);
    short4v o;
    o[0] = f2bf((x.x - mu) * rstd * gg.x + bb.x);
    o[1] = f2bf((x.y - mu) * rstd * gg.y + bb.y);
    o[2] = f2bf((x.z - mu) * rstd * gg.z + bb.z);
    o[3] = f2bf((x.w - mu) * rstd * gg.w + bb.w);
    *(short4v*)(out + (size_t)row * DIM + tid * 4) = o;
}

// ---------------- shared 128x128 GEMM core (BK=32, 4 waves 2x2, m97 structure) --------
template<int NK>
__device__ __forceinline__ void gemm_tile(
        const short* __restrict__ aBase, int as_,   // &A[rowbase][k0], row stride
        const short* __restrict__ bBase, int bs_,   // &B[colbase][k0], row stride
        short* As, short* Bs, f32x4 (&acc)[4][4]) {
    int tid = threadIdx.x;
    int lane = tid & 63, wave = tid >> 6;
    int wr = wave >> 1, wc = wave & 1;
    int r = lane & 15, ks = lane >> 4;
    int ldRow = tid >> 2;            // 0..63
    int ldCol = (tid & 3) * 8;       // element col within BK=32
    for (int kt = 0; kt < NK; ++kt) {
        __syncthreads();
        const short* aS = aBase + kt * 32;
        const short* bS = bBase + kt * 32;
        gload_lds16(As + (ldRow)      * 32 + ldCol, aS + (size_t)(ldRow)      * as_ + ldCol);
        gload_lds16(As + (ldRow + 64) * 32 + ldCol, aS + (size_t)(ldRow + 64) * as_ + ldCol);
        gload_lds16(Bs + (ldRow)      * 32 + ldCol, bS + (size_t)(ldRow)      * bs_ + ldCol);
        gload_lds16(Bs + (ldRow + 64) * 32 + ldCol, bS + (size_t)(ldRow + 64) * bs_ + ldCol);
        __syncthreads();
        bf16x8 a[4];
        #pragma unroll
        for (int m = 0; m < 4; ++m)
            a[m] = *(const bf16x8*)(As + (wr * 64 + m * 16 + r) * 32 + ks * 8);
        #pragma unroll
        for (int n = 0; n < 4; ++n) {
            bf16x8 b = *(const bf16x8*)(Bs + (wc * 64 + n * 16 + r) * 32 + ks * 8);
            #pragma unroll
            for (int m = 0; m < 4; ++m)
                acc[m][n] = __builtin_amdgcn_mfma_f32_16x16x32_bf16(a[m], b, acc[m][n], 0, 0, 0);
        }
    }
}

// ---------------- fused grouped QKV: per block (rowblock, group), loop q/k/v ----------
// Q written row-major [n][512]; K,V written group-major [g][PAD_ROWS][128]
__global__ __launch_bounds__(256) void qkv_kernel(
        const short* __restrict__ x,
        const short* __restrict__ wq, const short* __restrict__ wk, const short* __restrict__ wv,
        short* __restrict__ q, short* __restrict__ k, short* __restrict__ v) {
    __shared__ short As[128 * 32], Bs[128 * 32];
    int nwg = gridDim.x;             // 782*4 = 3128, %8==0
    int bid = blockIdx.x;
    int tile = (bid & 7) * (nwg >> 3) + (bid >> 3);
    int rb = tile >> 2, g = tile & 3;
    int rowbase = rb * 128;
    int tid = threadIdx.x;
    int lane = tid & 63, wave = tid >> 6;
    int wr = wave >> 1, wc = wave & 1;
    int r = lane & 15, ks = lane >> 4;
    const short* Ws[3] = {wq, wk, wv};
    short* Os[3] = {q, k, v};
    #pragma unroll
    for (int t = 0; t < 3; ++t) {
        f32x4 acc[4][4];
        #pragma unroll
        for (int m = 0; m < 4; ++m)
            #pragma unroll
            for (int n = 0; n < 4; ++n)
                #pragma unroll
                for (int e = 0; e < 4; ++e) acc[m][n][e] = 0.0f;
        gemm_tile<4>(x + (size_t)rowbase * DIM + g * GD, DIM,
                     Ws[t] + g * GD * GD, GD, As, Bs, acc);
        short* O = Os[t];
        #pragma unroll
        for (int m = 0; m < 4; ++m)
            #pragma unroll
            for (int n = 0; n < 4; ++n)
                #pragma unroll
                for (int rr = 0; rr < 4; ++rr) {
                    int orow = rowbase + wr * 64 + m * 16 + ks * 4 + rr;
                    int lcol = wc * 64 + n * 16 + r;
                    if (t == 0) {
                        O[(size_t)orow * DIM + g * GD + lcol] = f2bf(acc[m][n][rr]);
                    } else {
                        O[((size_t)g * PAD_ROWS + orow) * GD + lcol] = f2bf(acc[m][n][rr]);
                    }
                }
    }
}

// ---------------- attention: blockIdx.y = group (pass), 4 points/block, 1 wave each ---
// K,V group-major [g][PAD_ROWS][128]; per-pass gather working set = 51 MB (fits L3)
__global__ __launch_bounds__(256) void attn_kernel(
        const short* __restrict__ q, const short* __restrict__ kk, const short* __restrict__ vv,
        const int* __restrict__ nbrs, short* __restrict__ attn) {
    int g = blockIdx.y;
    int tid = threadIdx.x;
    int wv = tid >> 6, lane = tid & 63;
    int n = blockIdx.x * 4 + wv;           // 25000 * 4 = 100000 exact
    int s = lane >> 4, t = lane & 15;
    const float scale = 0.08838834764831845f; // 1/sqrt(128)
    // slot s owns neighbors {4s..4s+3}: one int4 load
    int4 nbj = *(const int4*)(nbrs + (size_t)n * K_NBR + s * 4);
    int nbarr[4] = {nbj.x, nbj.y, nbj.z, nbj.w};
    const short* kg = kk + (size_t)g * PAD_ROWS * GD;
    const short* vg = vv + (size_t)g * PAD_ROWS * GD;
    size_t qbase = (size_t)n * DIM + g * GD + t * 8;
    bf16x8 qf = *(const bf16x8*)(q + qbase);
    float qv[8];
    #pragma unroll
    for (int e = 0; e < 8; ++e) qv[e] = bf2f(qf[e]);
    // ---- QK^T ----
    float sc[4];
    #pragma unroll
    for (int p = 0; p < 4; ++p) {
        bf16x8 kf = *(const bf16x8*)(kg + (size_t)nbarr[p] * GD + t * 8);
        float d = 0.0f;
        #pragma unroll
        for (int e = 0; e < 8; ++e) d += qv[e] * bf2f(kf[e]);
        d += __shfl_xor(d, 1);
        d += __shfl_xor(d, 2);
        d += __shfl_xor(d, 4);
        d += __shfl_xor(d, 8);
        sc[p] = d * scale;
    }
    // ---- softmax over 16 neighbors (4 local + cross-slot) ----
    float mx = fmaxf(fmaxf(sc[0], sc[1]), fmaxf(sc[2], sc[3]));
    mx = fmaxf(mx, __shfl_xor(mx, 16));
    mx = fmaxf(mx, __shfl_xor(mx, 32));
    float ew[4]; float ssum = 0.0f;
    #pragma unroll
    for (int p = 0; p < 4; ++p) { ew[p] = __expf(sc[p] - mx); ssum += ew[p]; }
    ssum += __shfl_xor(ssum, 16);
    ssum += __shfl_xor(ssum, 32);
    // ---- PV: accumulate unnormalized, normalize once ----
    float acc[8];
    #pragma unroll
    for (int d0 = 0; d0 < 8; ++d0) acc[d0] = 0.0f;
    #pragma unroll
    for (int p = 0; p < 4; ++p) {
        bf16x8 vf = *(const bf16x8*)(vg + (size_t)nbarr[p] * GD + t * 8);
        #pragma unroll
        for (int d0 = 0; d0 < 8; ++d0) acc[d0] += ew[p] * bf2f(vf[d0]);
    }
    #pragma unroll
    for (int d0 = 0; d0 < 8; ++d0) {
        acc[d0] += __shfl_xor(acc[d0], 16);
        acc[d0] += __shfl_xor(acc[d0], 32);
    }
    if (s == 0) {
        float inv = 1.0f / ssum;
        bf16x8 o;
        #pragma unroll
        for (int d0 = 0; d0 < 8; ++d0) o[d0] = f2bf(acc[d0] * inv);
        *(bf16x8*)(attn + qbase) = o;
    }
}

// ---------------- out = attn @ Wo.T + bo + features (residual) -> f32 d_out ----------
__global__ __launch_bounds__(256) void outproj_kernel(
        const short* __restrict__ attn, const short* __restrict__ wo,
        const float* __restrict__ bo, const float* __restrict__ features,
        float* __restrict__ out) {
    __shared__ short As[128 * 32], Bs[128 * 32];
    int nwg = gridDim.x;             // 782*4
    int bid = blockIdx.x;
    int tile = (bid & 7) * (nwg >> 3) + (bid >> 3);
    int rb = tile >> 2, cb = tile & 3;
    int rowbase = rb * 128, colbase = cb * 128;
    int tid = threadIdx.x;
    int lane = tid & 63, wave = tid >> 6;
    int wr = wave >> 1, wc = wave & 1;
    int r = lane & 15, ks = lane >> 4;
    f32x4 acc[4][4];
    #pragma unroll
    for (int m = 0; m < 4; ++m)
        #pragma unroll
        for (int n = 0; n < 4; ++n)
            #pragma unroll
            for (int e = 0; e < 4; ++e) acc[m][n][e] = 0.0f;
    gemm_tile<16>(attn + (size_t)rowbase * DIM, DIM,
                  wo + (size_t)colbase * DIM, DIM, As, Bs, acc);
    #pragma unroll
    for (int m = 0; m < 4; ++m)
        #pragma unroll
        for (int n = 0; n < 4; ++n)
            #pragma unroll
            for (int rr = 0; rr < 4; ++rr) {
                int orow = rowbase + wr * 64 + m * 16 + ks * 4 + rr;
                int ocol = colbase + wc * 64 + n * 16 + r;
                if (orow < NPTS) {
                    out[(size_t)orow * DIM + ocol] =
                        acc[m][n][rr] + bo[ocol] + features[(size_t)orow * DIM + ocol];
                }
            }
}

// ---------------- FFN1: h = gelu(y @ W1.T + b1), bf16 out, N=1024 --------------------
__global__ __launch_bounds__(256) void ffn1_kernel(
        const short* __restrict__ y, const short* __restrict__ w1,
        const float* __restrict__ b1, short* __restrict__ h) {
    __shared__ short As[128 * 32], Bs[128 * 32];
    int nwg = gridDim.x;             // 782*8
    int bid = blockIdx.x;
    int tile = (bid & 7) * (nwg >> 3) + (bid >> 3);
    int rb = tile >> 3, cb = tile & 7;
    int rowbase = rb * 128, colbase = cb * 128;
    int tid = threadIdx.x;
    int lane = tid & 63, wave = tid >> 6;
    int wr = wave >> 1, wc = wave & 1;
    int r = lane & 15, ks = lane >> 4;
    f32x4 acc[4][4];
    #pragma unroll
    for (int m = 0; m < 4; ++m)
        #pragma unroll
        for (int n = 0; n < 4; ++n)
            #pragma unroll
            for (int e = 0; e < 4; ++e) acc[m][n][e] = 0.0f;
    gemm_tile<16>(y + (size_t)rowbase * DIM, DIM,
                  w1 + (size_t)colbase * DIM, DIM, As, Bs, acc);
    #pragma unroll
    for (int m = 0; m < 4; ++m)
        #pragma unroll
        for (int n = 0; n < 4; ++n)
            #pragma unroll
            for (int rr = 0; rr < 4; ++rr) {
                int orow = rowbase + wr * 64 + m * 16 + ks * 4 + rr;
                int ocol = colbase + wc * 64 + n * 16 + r;
                float xv = acc[m][n][rr] + b1[ocol];
                float gl = 0.5f * xv * (1.0f + erff(xv * 0.70710678118654752f));
                h[(size_t)orow * (2 * DIM) + ocol] = f2bf(gl);
            }
}

// ---------------- FFN2: d_out = h @ W2.T + b2 + d_out(res2), K=1024 ------------------
__global__ __launch_bounds__(256) void ffn2_kernel(
        const short* __restrict__ h, const short* __restrict__ w2,
        const float* __restrict__ b2, float* __restrict__ out) {
    __shared__ short As[128 * 32], Bs[128 * 32];
    int nwg = gridDim.x;             // 782*4
    int bid = blockIdx.x;
    int tile = (bid & 7) * (nwg >> 3) + (bid >> 3);
    int rb = tile >> 2, cb = tile & 3;
    int rowbase = rb * 128, colbase = cb * 128;
    int tid = threadIdx.x;
    int lane = tid & 63, wave = tid >> 6;
    int wr = wave >> 1, wc = wave & 1;
    int r = lane & 15, ks = lane >> 4;
    f32x4 acc[4][4];
    #pragma unroll
    for (int m = 0; m < 4; ++m)
        #pragma unroll
        for (int n = 0; n < 4; ++n)
            #pragma unroll
            for (int e = 0; e < 4; ++e) acc[m][n][e] = 0.0f;
    gemm_tile<32>(h + (size_t)rowbase * (2 * DIM), 2 * DIM,
                  w2 + (size_t)colbase * (2 * DIM), 2 * DIM, As, Bs, acc);
    #pragma unroll
    for (int m = 0; m < 4; ++m)
        #pragma unroll
        for (int n = 0; n < 4; ++n)
            #pragma unroll
            for (int rr = 0; rr < 4; ++rr) {
                int orow = rowbase + wr * 64 + m * 16 + ks * 4 + rr;
                int ocol = colbase + wc * 64 + n * 16 + r;
                if (orow < NPTS) {
                    size_t idx = (size_t)orow * DIM + ocol;
                    out[idx] = acc[m][n][rr] + b2[ocol] + out[idx];
                }
            }
}

extern "C" void kernel_launch(void* const* d_in, const int* in_sizes, int n_in,
                              void* d_out, int out_size, void* d_ws, size_t ws_size,
                              hipStream_t stream) {
    const float* features = (const float*)d_in[0];
    const int*   neighbors = (const int*)d_in[2];
    const float* Wq = (const float*)d_in[3];
    const float* Wk = (const float*)d_in[4];
    const float* Wv = (const float*)d_in[5];
    const float* Wo = (const float*)d_in[6];
    const float* bo = (const float*)d_in[7];
    const float* ln1_g = (const float*)d_in[8];
    const float* ln1_b = (const float*)d_in[9];
    const float* ln2_g = (const float*)d_in[10];
    const float* ln2_b = (const float*)d_in[11];
    const float* W1 = (const float*)d_in[12];
    const float* b1 = (const float*)d_in[13];
    const float* W2 = (const float*)d_in[14];
    const float* b2 = (const float*)d_in[15];
    float* out = (float*)d_out;

    size_t slotElems = (size_t)PAD_ROWS * DIM;
    short* s0 = (short*)d_ws;            // x -> attn
    short* s1 = s0 + slotElems;          // q -> y(ln2)
    short* s2 = s1 + slotElems;          // k (group-major) -> h (low half)
    short* s3 = s2 + slotElems;          // v (group-major) -> h (high half)
    short* wq_b = s3 + slotElems;
    short* wk_b = wq_b + GRP * GD * GD;
    short* wv_b = wk_b + GRP * GD * GD;
    short* wo_b = wv_b + GRP * GD * GD;
    short* w1_b = wo_b + DIM * DIM;
    short* w2_b = w1_b + 2 * DIM * DIM;

    cvt_kernel<<<128, 256, 0, stream>>>(Wq, wq_b, GRP * GD * GD);
    cvt_kernel<<<128, 256, 0, stream>>>(Wk, wk_b, GRP * GD * GD);
    cvt_kernel<<<128, 256, 0, stream>>>(Wv, wv_b, GRP * GD * GD);
    cvt_kernel<<<256, 256, 0, stream>>>(Wo, wo_b, DIM * DIM);
    cvt_kernel<<<256, 256, 0, stream>>>(W1, w1_b, 2 * DIM * DIM);
    cvt_kernel<<<256, 256, 0, stream>>>(W2, w2_b, 2 * DIM * DIM);

    // LN1: features -> x (bf16), zero-padded rows
    ln_kernel<<<PAD_ROWS, 128, 0, stream>>>(features, ln1_g, ln1_b, s0);

    // grouped QKV (fused q/k/v loop per block); K,V group-major
    qkv_kernel<<<(PAD_ROWS / 128) * 4, 256, 0, stream>>>(s0, wq_b, wk_b, wv_b, s1, s2, s3);

    // attention -> attn in s0 (row-major); per-group passes via blockIdx.y
    attn_kernel<<<dim3(NPTS / 4, GRP), 256, 0, stream>>>(s1, s2, s3, neighbors, s0);

    // out = attn @ Wo.T + bo + features  (f32, in d_out)
    outproj_kernel<<<(PAD_ROWS / 128) * 4, 256, 0, stream>>>(s0, wo_b, bo, features, out);

    // LN2: d_out -> y (bf16) in s1
    ln_kernel<<<PAD_ROWS, 128, 0, stream>>>(out, ln2_g, ln2_b, s1);

    // FFN1: h = gelu(y @ W1.T + b1) -> s2:s3 (P x 1024 bf16)
    ffn1_kernel<<<(PAD_ROWS / 128) * 8, 256, 0, stream>>>(s1, w1_b, b1, s2);

    // FFN2: d_out = h @ W2.T + b2 + d_out
    ffn2_kernel<<<(PAD_ROWS / 128) * 4, 256, 0, stream>>>(s2, w2_b, b2, out);
}

// Round 5
// 1423.063 us; speedup vs baseline: 1.0439x; 1.0241x over previous
//
#include <hip/hip_runtime.h>
#include <hip/hip_bf16.h>
#include <math.h>

#define NPTS 100000
#define PAD_ROWS 100096   // 782 * 128
#define DIM 512
#define GRP 4
#define GD 128
#define K_NBR 16
#define EPS 1e-5f

using bf16x8 = __attribute__((ext_vector_type(8))) short;
using f32x4  = __attribute__((ext_vector_type(4))) float;
using short4v = __attribute__((ext_vector_type(4))) short;

__device__ inline float bf2f(short s) {
    unsigned u = ((unsigned)(unsigned short)s) << 16;
    union { unsigned u; float f; } c; c.u = u; return c.f;
}
__device__ inline short f2bf(float f) {
    union { float f; unsigned u; } c; c.f = f;
    unsigned u = c.u;
    unsigned r = (u + 0x7fffu + ((u >> 16) & 1u)) >> 16;
    return (short)r;
}

__device__ __forceinline__ void gload_lds16(short* lds, const short* g) {
    __builtin_amdgcn_global_load_lds(
        (const __attribute__((address_space(1))) unsigned int*)g,
        (__attribute__((address_space(3))) unsigned int*)lds, 16, 0, 0);
}

// ---------------- weight convert f32 -> bf16 ----------------
__global__ void cvt_kernel(const float* __restrict__ src, short* __restrict__ dst, int n) {
    int i = blockIdx.x * blockDim.x + threadIdx.x;
    int stride = gridDim.x * blockDim.x;
    for (; i < n; i += stride) dst[i] = f2bf(src[i]);
}

// ---------------- LayerNorm (f32 in -> bf16 out) ----------------
__global__ void ln_kernel(const float* __restrict__ in, const float* __restrict__ g,
                          const float* __restrict__ b, short* __restrict__ out) {
    int row = blockIdx.x;
    int tid = threadIdx.x; // 128 threads, 4 elems each
    if (row >= NPTS) {
        short4v z; z[0] = 0; z[1] = 0; z[2] = 0; z[3] = 0;
        *(short4v*)(out + (size_t)row * DIM + tid * 4) = z;
        return;
    }
    const float4 x = *(const float4*)(in + (size_t)row * DIM + tid * 4);
    float s  = x.x + x.y + x.z + x.w;
    float sq = x.x * x.x + x.y * x.y + x.z * x.z + x.w * x.w;
    for (int m = 1; m < 64; m <<= 1) {
        s  += __shfl_xor(s, m);
        sq += __shfl_xor(sq, m);
    }
    __shared__ float ss[2], ssq[2];
    int wv = tid >> 6;
    if ((tid & 63) == 0) { ss[wv] = s; ssq[wv] = sq; }
    __syncthreads();
    s = ss[0] + ss[1]; sq = ssq[0] + ssq[1];
    float mu = s * (1.0f / DIM);
    float var = sq * (1.0f / DIM) - mu * mu;
    float rstd = rsqrtf(var + EPS);
    const float4 gg = *(const float4*)(g + tid * 4);
    const float4 bb = *(const float4*)(b + tid * 4);
    short4v o;
    o[0] = f2bf((x.x - mu) * rstd * gg.x + bb.x);
    o[1] = f2bf((x.y - mu) * rstd * gg.y + bb.y);
    o[2] = f2bf((x.z - mu) * rstd * gg.z + bb.z);
    o[3] = f2bf((x.w - mu) * rstd * gg.w + bb.w);
    *(short4v*)(out + (size_t)row * DIM + tid * 4) = o;
}

// ---------------- shared 128x128 GEMM core (BK=32, 4 waves 2x2, m97 structure) --------
template<int NK>
__device__ __forceinline__ void gemm_tile(
        const short* __restrict__ aBase, int as_,   // &A[rowbase][k0], row stride
        const short* __restrict__ bBase, int bs_,   // &B[colbase][k0], row stride
        short* As, short* Bs, f32x4 (&acc)[4][4]) {
    int tid = threadIdx.x;
    int lane = tid & 63, wave = tid >> 6;
    int wr = wave >> 1, wc = wave & 1;
    int r = lane & 15, ks = lane >> 4;
    int ldRow = tid >> 2;            // 0..63
    int ldCol = (tid & 3) * 8;       // element col within BK=32
    for (int kt = 0; kt < NK; ++kt) {
        __syncthreads();
        const short* aS = aBase + kt * 32;
        const short* bS = bBase + kt * 32;
        gload_lds16(As + (ldRow)      * 32 + ldCol, aS + (size_t)(ldRow)      * as_ + ldCol);
        gload_lds16(As + (ldRow + 64) * 32 + ldCol, aS + (size_t)(ldRow + 64) * as_ + ldCol);
        gload_lds16(Bs + (ldRow)      * 32 + ldCol, bS + (size_t)(ldRow)      * bs_ + ldCol);
        gload_lds16(Bs + (ldRow + 64) * 32 + ldCol, bS + (size_t)(ldRow + 64) * bs_ + ldCol);
        __syncthreads();
        bf16x8 a[4];
        #pragma unroll
        for (int m = 0; m < 4; ++m)
            a[m] = *(const bf16x8*)(As + (wr * 64 + m * 16 + r) * 32 + ks * 8);
        #pragma unroll
        for (int n = 0; n < 4; ++n) {
            bf16x8 b = *(const bf16x8*)(Bs + (wc * 64 + n * 16 + r) * 32 + ks * 8);
            #pragma unroll
            for (int m = 0; m < 4; ++m)
                acc[m][n] = __builtin_amdgcn_mfma_f32_16x16x32_bf16(a[m], b, acc[m][n], 0, 0, 0);
        }
    }
}

// ---------------- fused grouped QKV: per block (rowblock, group), loop q/k/v ----------
// Q written row-major [n][512]; K,V written group-major [g][PAD_ROWS][128]
__global__ __launch_bounds__(256) void qkv_kernel(
        const short* __restrict__ x,
        const short* __restrict__ wq, const short* __restrict__ wk, const short* __restrict__ wv,
        short* __restrict__ q, short* __restrict__ k, short* __restrict__ v) {
    __shared__ short As[128 * 32], Bs[128 * 32];
    int nwg = gridDim.x;             // 782*4 = 3128, %8==0
    int bid = blockIdx.x;
    int tile = (bid & 7) * (nwg >> 3) + (bid >> 3);
    int rb = tile >> 2, g = tile & 3;
    int rowbase = rb * 128;
    int tid = threadIdx.x;
    int lane = tid & 63, wave = tid >> 6;
    int wr = wave >> 1, wc = wave & 1;
    int r = lane & 15, ks = lane >> 4;
    const short* Ws[3] = {wq, wk, wv};
    short* Os[3] = {q, k, v};
    #pragma unroll
    for (int t = 0; t < 3; ++t) {
        f32x4 acc[4][4];
        #pragma unroll
        for (int m = 0; m < 4; ++m)
            #pragma unroll
            for (int n = 0; n < 4; ++n)
                #pragma unroll
                for (int e = 0; e < 4; ++e) acc[m][n][e] = 0.0f;
        gemm_tile<4>(x + (size_t)rowbase * DIM + g * GD, DIM,
                     Ws[t] + g * GD * GD, GD, As, Bs, acc);
        short* O = Os[t];
        #pragma unroll
        for (int m = 0; m < 4; ++m)
            #pragma unroll
            for (int n = 0; n < 4; ++n)
                #pragma unroll
                for (int rr = 0; rr < 4; ++rr) {
                    int orow = rowbase + wr * 64 + m * 16 + ks * 4 + rr;
                    int lcol = wc * 64 + n * 16 + r;
                    if (t == 0) {
                        O[(size_t)orow * DIM + g * GD + lcol] = f2bf(acc[m][n][rr]);
                    } else {
                        O[((size_t)g * PAD_ROWS + orow) * GD + lcol] = f2bf(acc[m][n][rr]);
                    }
                }
    }
}

// ---------------- attention: XCD-affine gather ---------------------------------------
// blockIdx.x in [0,100000): xcd = b&7, group = xcd>>1, quad = (b>>3)*2 + (xcd&1).
// With round-robin block->XCD dispatch, each XCD gathers only its group's 51 MB
// K/V slice -> L2-miss replication drops 8x -> 2x. 4 points/block, 1 wave each.
__global__ __launch_bounds__(256) void attn_kernel(
        const short* __restrict__ q, const short* __restrict__ kk, const short* __restrict__ vv,
        const int* __restrict__ nbrs, short* __restrict__ attn) {
    int b = blockIdx.x;
    int xcd = b & 7;
    int g = xcd >> 1;
    int quad = (b >> 3) * 2 + (xcd & 1);   // 0..24999
    int tid = threadIdx.x;
    int wv = tid >> 6, lane = tid & 63;
    int n = quad * 4 + wv;                 // 0..99999
    int s = lane >> 4, t = lane & 15;
    const float scale = 0.08838834764831845f; // 1/sqrt(128)
    // slot s owns neighbors {4s..4s+3}: one int4 load
    int4 nbj = *(const int4*)(nbrs + (size_t)n * K_NBR + s * 4);
    int nbarr[4] = {nbj.x, nbj.y, nbj.z, nbj.w};
    const short* kg = kk + (size_t)g * PAD_ROWS * GD;
    const short* vg = vv + (size_t)g * PAD_ROWS * GD;
    size_t qbase = (size_t)n * DIM + g * GD + t * 8;
    bf16x8 qf = *(const bf16x8*)(q + qbase);
    float qv[8];
    #pragma unroll
    for (int e = 0; e < 8; ++e) qv[e] = bf2f(qf[e]);
    // ---- QK^T: local partial dots (4 K gathers in flight together) ----
    float d[4];
    #pragma unroll
    for (int p = 0; p < 4; ++p) {
        bf16x8 kf = *(const bf16x8*)(kg + (size_t)nbarr[p] * GD + t * 8);
        float dd = 0.0f;
        #pragma unroll
        for (int e = 0; e < 8; ++e) dd += qv[e] * bf2f(kf[e]);
        d[p] = dd;
    }
    // ---- hoist V gathers: latency hides under the shuffle chains below ----
    bf16x8 vf[4];
    #pragma unroll
    for (int p = 0; p < 4; ++p)
        vf[p] = *(const bf16x8*)(vg + (size_t)nbarr[p] * GD + t * 8);
    // ---- reduce dots across 16 dim-lanes ----
    float sc[4];
    #pragma unroll
    for (int p = 0; p < 4; ++p) {
        float dd = d[p];
        dd += __shfl_xor(dd, 1);
        dd += __shfl_xor(dd, 2);
        dd += __shfl_xor(dd, 4);
        dd += __shfl_xor(dd, 8);
        sc[p] = dd * scale;
    }
    // ---- softmax over 16 neighbors (4 local + cross-slot) ----
    float mx = fmaxf(fmaxf(sc[0], sc[1]), fmaxf(sc[2], sc[3]));
    mx = fmaxf(mx, __shfl_xor(mx, 16));
    mx = fmaxf(mx, __shfl_xor(mx, 32));
    float ew[4]; float ssum = 0.0f;
    #pragma unroll
    for (int p = 0; p < 4; ++p) { ew[p] = __expf(sc[p] - mx); ssum += ew[p]; }
    ssum += __shfl_xor(ssum, 16);
    ssum += __shfl_xor(ssum, 32);
    // ---- PV: accumulate unnormalized, normalize once ----
    float acc[8];
    #pragma unroll
    for (int d0 = 0; d0 < 8; ++d0) acc[d0] = 0.0f;
    #pragma unroll
    for (int p = 0; p < 4; ++p) {
        #pragma unroll
        for (int d0 = 0; d0 < 8; ++d0) acc[d0] += ew[p] * bf2f(vf[p][d0]);
    }
    #pragma unroll
    for (int d0 = 0; d0 < 8; ++d0) {
        acc[d0] += __shfl_xor(acc[d0], 16);
        acc[d0] += __shfl_xor(acc[d0], 32);
    }
    if (s == 0) {
        float inv = 1.0f / ssum;
        bf16x8 o;
        #pragma unroll
        for (int d0 = 0; d0 < 8; ++d0) o[d0] = f2bf(acc[d0] * inv);
        *(bf16x8*)(attn + qbase) = o;
    }
}

// ---------------- out = attn @ Wo.T + bo + features (residual) -> f32 d_out ----------
__global__ __launch_bounds__(256) void outproj_kernel(
        const short* __restrict__ attn, const short* __restrict__ wo,
        const float* __restrict__ bo, const float* __restrict__ features,
        float* __restrict__ out) {
    __shared__ short As[128 * 32], Bs[128 * 32];
    int nwg = gridDim.x;             // 782*4
    int bid = blockIdx.x;
    int tile = (bid & 7) * (nwg >> 3) + (bid >> 3);
    int rb = tile >> 2, cb = tile & 3;
    int rowbase = rb * 128, colbase = cb * 128;
    int tid = threadIdx.x;
    int lane = tid & 63, wave = tid >> 6;
    int wr = wave >> 1, wc = wave & 1;
    int r = lane & 15, ks = lane >> 4;
    f32x4 acc[4][4];
    #pragma unroll
    for (int m = 0; m < 4; ++m)
        #pragma unroll
        for (int n = 0; n < 4; ++n)
            #pragma unroll
            for (int e = 0; e < 4; ++e) acc[m][n][e] = 0.0f;
    gemm_tile<16>(attn + (size_t)rowbase * DIM, DIM,
                  wo + (size_t)colbase * DIM, DIM, As, Bs, acc);
    #pragma unroll
    for (int m = 0; m < 4; ++m)
        #pragma unroll
        for (int n = 0; n < 4; ++n)
            #pragma unroll
            for (int rr = 0; rr < 4; ++rr) {
                int orow = rowbase + wr * 64 + m * 16 + ks * 4 + rr;
                int ocol = colbase + wc * 64 + n * 16 + r;
                if (orow < NPTS) {
                    out[(size_t)orow * DIM + ocol] =
                        acc[m][n][rr] + bo[ocol] + features[(size_t)orow * DIM + ocol];
                }
            }
}

// ---------------- FFN1: h = gelu(y @ W1.T + b1), bf16 out, N=1024 --------------------
__global__ __launch_bounds__(256) void ffn1_kernel(
        const short* __restrict__ y, const short* __restrict__ w1,
        const float* __restrict__ b1, short* __restrict__ h) {
    __shared__ short As[128 * 32], Bs[128 * 32];
    int nwg = gridDim.x;             // 782*8
    int bid = blockIdx.x;
    int tile = (bid & 7) * (nwg >> 3) + (bid >> 3);
    int rb = tile >> 3, cb = tile & 7;
    int rowbase = rb * 128, colbase = cb * 128;
    int tid = threadIdx.x;
    int lane = tid & 63, wave = tid >> 6;
    int wr = wave >> 1, wc = wave & 1;
    int r = lane & 15, ks = lane >> 4;
    f32x4 acc[4][4];
    #pragma unroll
    for (int m = 0; m < 4; ++m)
        #pragma unroll
        for (int n = 0; n < 4; ++n)
            #pragma unroll
            for (int e = 0; e < 4; ++e) acc[m][n][e] = 0.0f;
    gemm_tile<16>(y + (size_t)rowbase * DIM, DIM,
                  w1 + (size_t)colbase * DIM, DIM, As, Bs, acc);
    #pragma unroll
    for (int m = 0; m < 4; ++m)
        #pragma unroll
        for (int n = 0; n < 4; ++n)
            #pragma unroll
            for (int rr = 0; rr < 4; ++rr) {
                int orow = rowbase + wr * 64 + m * 16 + ks * 4 + rr;
                int ocol = colbase + wc * 64 + n * 16 + r;
                float xv = acc[m][n][rr] + b1[ocol];
                // exact-GELU via clamped tanh form (max abs err ~3e-3, << bf16 out rounding path)
                float xc = fminf(fmaxf(xv, -9.0f), 9.0f);
                float u = xc * (0.7978845608028654f + 0.0356774081f * xc * xc);
                float e2 = __expf(2.0f * u);
                float th = (e2 - 1.0f) / (e2 + 1.0f);
                float gl = 0.5f * xv * (1.0f + th);
                h[(size_t)orow * (2 * DIM) + ocol] = f2bf(gl);
            }
}

// ---------------- FFN2: d_out = h @ W2.T + b2 + d_out(res2), K=1024 ------------------
__global__ __launch_bounds__(256) void ffn2_kernel(
        const short* __restrict__ h, const short* __restrict__ w2,
        const float* __restrict__ b2, float* __restrict__ out) {
    __shared__ short As[128 * 32], Bs[128 * 32];
    int nwg = gridDim.x;             // 782*4
    int bid = blockIdx.x;
    int tile = (bid & 7) * (nwg >> 3) + (bid >> 3);
    int rb = tile >> 2, cb = tile & 3;
    int rowbase = rb * 128, colbase = cb * 128;
    int tid = threadIdx.x;
    int lane = tid & 63, wave = tid >> 6;
    int wr = wave >> 1, wc = wave & 1;
    int r = lane & 15, ks = lane >> 4;
    f32x4 acc[4][4];
    #pragma unroll
    for (int m = 0; m < 4; ++m)
        #pragma unroll
        for (int n = 0; n < 4; ++n)
            #pragma unroll
            for (int e = 0; e < 4; ++e) acc[m][n][e] = 0.0f;
    gemm_tile<32>(h + (size_t)rowbase * (2 * DIM), 2 * DIM,
                  w2 + (size_t)colbase * (2 * DIM), 2 * DIM, As, Bs, acc);
    #pragma unroll
    for (int m = 0; m < 4; ++m)
        #pragma unroll
        for (int n = 0; n < 4; ++n)
            #pragma unroll
            for (int rr = 0; rr < 4; ++rr) {
                int orow = rowbase + wr * 64 + m * 16 + ks * 4 + rr;
                int ocol = colbase + wc * 64 + n * 16 + r;
                if (orow < NPTS) {
                    size_t idx = (size_t)orow * DIM + ocol;
                    out[idx] = acc[m][n][rr] + b2[ocol] + out[idx];
                }
            }
}

extern "C" void kernel_launch(void* const* d_in, const int* in_sizes, int n_in,
                              void* d_out, int out_size, void* d_ws, size_t ws_size,
                              hipStream_t stream) {
    const float* features = (const float*)d_in[0];
    const int*   neighbors = (const int*)d_in[2];
    const float* Wq = (const float*)d_in[3];
    const float* Wk = (const float*)d_in[4];
    const float* Wv = (const float*)d_in[5];
    const float* Wo = (const float*)d_in[6];
    const float* bo = (const float*)d_in[7];
    const float* ln1_g = (const float*)d_in[8];
    const float* ln1_b = (const float*)d_in[9];
    const float* ln2_g = (const float*)d_in[10];
    const float* ln2_b = (const float*)d_in[11];
    const float* W1 = (const float*)d_in[12];
    const float* b1 = (const float*)d_in[13];
    const float* W2 = (const float*)d_in[14];
    const float* b2 = (const float*)d_in[15];
    float* out = (float*)d_out;

    size_t slotElems = (size_t)PAD_ROWS * DIM;
    short* s0 = (short*)d_ws;            // x -> attn
    short* s1 = s0 + slotElems;          // q -> y(ln2)
    short* s2 = s1 + slotElems;          // k (group-major) -> h (low half)
    short* s3 = s2 + slotElems;          // v (group-major) -> h (high half)
    short* wq_b = s3 + slotElems;
    short* wk_b = wq_b + GRP * GD * GD;
    short* wv_b = wk_b + GRP * GD * GD;
    short* wo_b = wv_b + GRP * GD * GD;
    short* w1_b = wo_b + DIM * DIM;
    short* w2_b = w1_b + 2 * DIM * DIM;

    cvt_kernel<<<128, 256, 0, stream>>>(Wq, wq_b, GRP * GD * GD);
    cvt_kernel<<<128, 256, 0, stream>>>(Wk, wk_b, GRP * GD * GD);
    cvt_kernel<<<128, 256, 0, stream>>>(Wv, wv_b, GRP * GD * GD);
    cvt_kernel<<<256, 256, 0, stream>>>(Wo, wo_b, DIM * DIM);
    cvt_kernel<<<256, 256, 0, stream>>>(W1, w1_b, 2 * DIM * DIM);
    cvt_kernel<<<256, 256, 0, stream>>>(W2, w2_b, 2 * DIM * DIM);

    // LN1: features -> x (bf16), zero-padded rows
    ln_kernel<<<PAD_ROWS, 128, 0, stream>>>(features, ln1_g, ln1_b, s0);

    // grouped QKV (fused q/k/v loop per block); K,V group-major
    qkv_kernel<<<(PAD_ROWS / 128) * 4, 256, 0, stream>>>(s0, wq_b, wk_b, wv_b, s1, s2, s3);

    // attention -> attn in s0 (row-major); XCD-affine group mapping, 12500*8 blocks
    attn_kernel<<<NPTS, 256, 0, stream>>>(s1, s2, s3, neighbors, s0);

    // out = attn @ Wo.T + bo + features  (f32, in d_out)
    outproj_kernel<<<(PAD_ROWS / 128) * 4, 256, 0, stream>>>(s0, wo_b, bo, features, out);

    // LN2: d_out -> y (bf16) in s1
    ln_kernel<<<PAD_ROWS, 128, 0, stream>>>(out, ln2_g, ln2_b, s1);

    // FFN1: h = gelu(y @ W1.T + b1) -> s2:s3 (P x 1024 bf16)
    ffn1_kernel<<<(PAD_ROWS / 128) * 8, 256, 0, stream>>>(s1, w1_b, b1, s2);

    // FFN2: d_out = h @ W2.T + b2 + d_out
    ffn2_kernel<<<(PAD_ROWS / 128) * 4, 256, 0, stream>>>(s2, w2_b, b2, out);
}

// Round 6
// 1164.422 us; speedup vs baseline: 1.2757x; 1.2221x over previous
//
#include <hip/hip_runtime.h>
#include <hip/hip_bf16.h>
#include <math.h>

#define NPTS 100000
#define PAD_ROWS 100096   // 782 * 128
#define DIM 512
#define GRP 4
#define GD 128
#define K_NBR 16
#define EPS 1e-5f

using bf16x8 = __attribute__((ext_vector_type(8))) short;
using f32x4  = __attribute__((ext_vector_type(4))) float;
using short4v = __attribute__((ext_vector_type(4))) short;

__device__ inline float bf2f(short s) {
    unsigned u = ((unsigned)(unsigned short)s) << 16;
    union { unsigned u; float f; } c; c.u = u; return c.f;
}
__device__ inline short f2bf(float f) {
    union { float f; unsigned u; } c; c.f = f;
    unsigned u = c.u;
    unsigned r = (u + 0x7fffu + ((u >> 16) & 1u)) >> 16;
    return (short)r;
}

__device__ __forceinline__ void gload_lds16(short* lds, const short* g) {
    __builtin_amdgcn_global_load_lds(
        (const __attribute__((address_space(1))) unsigned int*)g,
        (__attribute__((address_space(3))) unsigned int*)lds, 16, 0, 0);
}

// ---------------- weight convert f32 -> bf16 ----------------
__global__ void cvt_kernel(const float* __restrict__ src, short* __restrict__ dst, int n) {
    int i = blockIdx.x * blockDim.x + threadIdx.x;
    int stride = gridDim.x * blockDim.x;
    for (; i < n; i += stride) dst[i] = f2bf(src[i]);
}

// ---------------- Mt[g][e][d] = scale * sum_o Wq[g][o][d] * Wk[g][o][e] --------------
// (q' = Mt x gives score q'.x_j == scale * (Wq x_i).(Wk x_j))
__global__ void prep_m_kernel(const float* __restrict__ wq, const float* __restrict__ wk,
                              short* __restrict__ mt) {
    int ge = blockIdx.x;            // g*128 + e
    int g = ge >> 7, e = ge & 127;
    int d = threadIdx.x;            // 128 threads
    const float* Wq = wq + (size_t)g * GD * GD;
    const float* Wk = wk + (size_t)g * GD * GD;
    float acc = 0.0f;
    for (int o = 0; o < GD; ++o)
        acc += Wq[(size_t)o * GD + d] * Wk[(size_t)o * GD + e];
    mt[(size_t)ge * GD + d] = f2bf(acc * 0.08838834764831845f);
}

// ---------------- Wov[o][g*128+i0] = sum_d Wo[o][g*128+d] * Wv[g][d][i0] -------------
// (t @ Wov.T == (blockdiag(Wv) t) @ Wo.T)
__global__ void prep_wov_kernel(const float* __restrict__ wo, const float* __restrict__ wv,
                                short* __restrict__ wov) {
    int o = blockIdx.x;             // 512 blocks
    int i = threadIdx.x;            // 512 threads
    int g = i >> 7, i0 = i & 127;
    float acc = 0.0f;
    for (int d = 0; d < GD; ++d)
        acc += wo[(size_t)o * DIM + g * GD + d] * wv[((size_t)g * GD + d) * GD + i0];
    wov[(size_t)o * DIM + i] = f2bf(acc);
}

// ---------------- LayerNorm (f32 in -> bf16 out) ----------------
__global__ void ln_kernel(const float* __restrict__ in, const float* __restrict__ g,
                          const float* __restrict__ b, short* __restrict__ out) {
    int row = blockIdx.x;
    int tid = threadIdx.x; // 128 threads, 4 elems each
    if (row >= NPTS) {
        short4v z; z[0] = 0; z[1] = 0; z[2] = 0; z[3] = 0;
        *(short4v*)(out + (size_t)row * DIM + tid * 4) = z;
        return;
    }
    const float4 x = *(const float4*)(in + (size_t)row * DIM + tid * 4);
    float s  = x.x + x.y + x.z + x.w;
    float sq = x.x * x.x + x.y * x.y + x.z * x.z + x.w * x.w;
    for (int m = 1; m < 64; m <<= 1) {
        s  += __shfl_xor(s, m);
        sq += __shfl_xor(sq, m);
    }
    __shared__ float ss[2], ssq[2];
    int wv = tid >> 6;
    if ((tid & 63) == 0) { ss[wv] = s; ssq[wv] = sq; }
    __syncthreads();
    s = ss[0] + ss[1]; sq = ssq[0] + ssq[1];
    float mu = s * (1.0f / DIM);
    float var = sq * (1.0f / DIM) - mu * mu;
    float rstd = rsqrtf(var + EPS);
    const float4 gg = *(const float4*)(g + tid * 4);
    const float4 bb = *(const float4*)(b + tid * 4);
    short4v o;
    o[0] = f2bf((x.x - mu) * rstd * gg.x + bb.x);
    o[1] = f2bf((x.y - mu) * rstd * gg.y + bb.y);
    o[2] = f2bf((x.z - mu) * rstd * gg.z + bb.z);
    o[3] = f2bf((x.w - mu) * rstd * gg.w + bb.w);
    *(short4v*)(out + (size_t)row * DIM + tid * 4) = o;
}

// ---------------- shared 128x128 GEMM core (BK=32, 4 waves 2x2, m97 structure) --------
template<int NK>
__device__ __forceinline__ void gemm_tile(
        const short* __restrict__ aBase, int as_,   // &A[rowbase][k0], row stride
        const short* __restrict__ bBase, int bs_,   // &B[colbase][k0], row stride
        short* As, short* Bs, f32x4 (&acc)[4][4]) {
    int tid = threadIdx.x;
    int lane = tid & 63, wave = tid >> 6;
    int wr = wave >> 1, wc = wave & 1;
    int r = lane & 15, ks = lane >> 4;
    int ldRow = tid >> 2;            // 0..63
    int ldCol = (tid & 3) * 8;       // element col within BK=32
    for (int kt = 0; kt < NK; ++kt) {
        __syncthreads();
        const short* aS = aBase + kt * 32;
        const short* bS = bBase + kt * 32;
        gload_lds16(As + (ldRow)      * 32 + ldCol, aS + (size_t)(ldRow)      * as_ + ldCol);
        gload_lds16(As + (ldRow + 64) * 32 + ldCol, aS + (size_t)(ldRow + 64) * as_ + ldCol);
        gload_lds16(Bs + (ldRow)      * 32 + ldCol, bS + (size_t)(ldRow)      * bs_ + ldCol);
        gload_lds16(Bs + (ldRow + 64) * 32 + ldCol, bS + (size_t)(ldRow + 64) * bs_ + ldCol);
        __syncthreads();
        bf16x8 a[4];
        #pragma unroll
        for (int m = 0; m < 4; ++m)
            a[m] = *(const bf16x8*)(As + (wr * 64 + m * 16 + r) * 32 + ks * 8);
        #pragma unroll
        for (int n = 0; n < 4; ++n) {
            bf16x8 b = *(const bf16x8*)(Bs + (wc * 64 + n * 16 + r) * 32 + ks * 8);
            #pragma unroll
            for (int m = 0; m < 4; ++m)
                acc[m][n] = __builtin_amdgcn_mfma_f32_16x16x32_bf16(a[m], b, acc[m][n], 0, 0, 0);
        }
    }
}

// ---------------- q' projection: q'[n][g*128+e] = sum_d x[n][g*128+d] * Mt[g][e][d] ---
__global__ __launch_bounds__(256) void qproj_kernel(
        const short* __restrict__ x, const short* __restrict__ mt,
        short* __restrict__ qp) {
    __shared__ short As[128 * 32], Bs[128 * 32];
    int nwg = gridDim.x;             // 782*4 = 3128, %8==0
    int bid = blockIdx.x;
    int tile = (bid & 7) * (nwg >> 3) + (bid >> 3);
    int rb = tile >> 2, g = tile & 3;
    int rowbase = rb * 128;
    int tid = threadIdx.x;
    int lane = tid & 63, wave = tid >> 6;
    int wr = wave >> 1, wc = wave & 1;
    int r = lane & 15, ks = lane >> 4;
    f32x4 acc[4][4];
    #pragma unroll
    for (int m = 0; m < 4; ++m)
        #pragma unroll
        for (int n = 0; n < 4; ++n)
            #pragma unroll
            for (int e = 0; e < 4; ++e) acc[m][n][e] = 0.0f;
    gemm_tile<4>(x + (size_t)rowbase * DIM + g * GD, DIM,
                 mt + (size_t)g * GD * GD, GD, As, Bs, acc);
    #pragma unroll
    for (int m = 0; m < 4; ++m)
        #pragma unroll
        for (int n = 0; n < 4; ++n)
            #pragma unroll
            for (int rr = 0; rr < 4; ++rr) {
                int orow = rowbase + wr * 64 + m * 16 + ks * 4 + rr;
                int lcol = wc * 64 + n * 16 + r;
                qp[(size_t)orow * DIM + g * GD + lcol] = f2bf(acc[m][n][rr]);
            }
}

// ---------------- attention: gathers x only; t[n][g] = sum_j softmax_j * x_j[g-slice] -
// score = q'.x_j (scale folded into Mt). XCD-affine group mapping retained.
__global__ __launch_bounds__(256) void attn_kernel(
        const short* __restrict__ qp, const short* __restrict__ x,
        const int* __restrict__ nbrs, short* __restrict__ t_out) {
    int b = blockIdx.x;
    int xcd = b & 7;
    int g = xcd >> 1;
    int quad = (b >> 3) * 2 + (xcd & 1);   // 0..24999
    int tid = threadIdx.x;
    int wv = tid >> 6, lane = tid & 63;
    int n = quad * 4 + wv;                 // 0..99999
    int s = lane >> 4, t = lane & 15;
    // slot s owns neighbors {4s..4s+3}: one int4 load
    int4 nbj = *(const int4*)(nbrs + (size_t)n * K_NBR + s * 4);
    int nbarr[4] = {nbj.x, nbj.y, nbj.z, nbj.w};
    size_t goff = (size_t)g * GD + t * 8;
    size_t qbase = (size_t)n * DIM + goff;
    bf16x8 qf = *(const bf16x8*)(qp + qbase);
    float qv[8];
    #pragma unroll
    for (int e = 0; e < 8; ++e) qv[e] = bf2f(qf[e]);
    // ---- gather x slices once; serve both score and weighted sum ----
    bf16x8 xf[4];
    #pragma unroll
    for (int p = 0; p < 4; ++p)
        xf[p] = *(const bf16x8*)(x + (size_t)nbarr[p] * DIM + goff);
    // ---- dots ----
    float sc[4];
    #pragma unroll
    for (int p = 0; p < 4; ++p) {
        float dd = 0.0f;
        #pragma unroll
        for (int e = 0; e < 8; ++e) dd += qv[e] * bf2f(xf[p][e]);
        dd += __shfl_xor(dd, 1);
        dd += __shfl_xor(dd, 2);
        dd += __shfl_xor(dd, 4);
        dd += __shfl_xor(dd, 8);
        sc[p] = dd;
    }
    // ---- softmax over 16 neighbors (4 local + cross-slot) ----
    float mx = fmaxf(fmaxf(sc[0], sc[1]), fmaxf(sc[2], sc[3]));
    mx = fmaxf(mx, __shfl_xor(mx, 16));
    mx = fmaxf(mx, __shfl_xor(mx, 32));
    float ew[4]; float ssum = 0.0f;
    #pragma unroll
    for (int p = 0; p < 4; ++p) { ew[p] = __expf(sc[p] - mx); ssum += ew[p]; }
    ssum += __shfl_xor(ssum, 16);
    ssum += __shfl_xor(ssum, 32);
    // ---- weighted sum of gathered x slices ----
    float acc[8];
    #pragma unroll
    for (int d0 = 0; d0 < 8; ++d0) acc[d0] = 0.0f;
    #pragma unroll
    for (int p = 0; p < 4; ++p) {
        #pragma unroll
        for (int d0 = 0; d0 < 8; ++d0) acc[d0] += ew[p] * bf2f(xf[p][d0]);
    }
    #pragma unroll
    for (int d0 = 0; d0 < 8; ++d0) {
        acc[d0] += __shfl_xor(acc[d0], 16);
        acc[d0] += __shfl_xor(acc[d0], 32);
    }
    if (s == 0) {
        float inv = 1.0f / ssum;
        bf16x8 o;
        #pragma unroll
        for (int d0 = 0; d0 < 8; ++d0) o[d0] = f2bf(acc[d0] * inv);
        *(bf16x8*)(t_out + qbase) = o;
    }
}

// ---------------- out = t @ Wov.T + bo + features (residual) -> f32 d_out -------------
__global__ __launch_bounds__(256) void outproj_kernel(
        const short* __restrict__ tbuf, const short* __restrict__ wov,
        const float* __restrict__ bo, const float* __restrict__ features,
        float* __restrict__ out) {
    __shared__ short As[128 * 32], Bs[128 * 32];
    int nwg = gridDim.x;             // 782*4
    int bid = blockIdx.x;
    int tile = (bid & 7) * (nwg >> 3) + (bid >> 3);
    int rb = tile >> 2, cb = tile & 3;
    int rowbase = rb * 128, colbase = cb * 128;
    int tid = threadIdx.x;
    int lane = tid & 63, wave = tid >> 6;
    int wr = wave >> 1, wc = wave & 1;
    int r = lane & 15, ks = lane >> 4;
    f32x4 acc[4][4];
    #pragma unroll
    for (int m = 0; m < 4; ++m)
        #pragma unroll
        for (int n = 0; n < 4; ++n)
            #pragma unroll
            for (int e = 0; e < 4; ++e) acc[m][n][e] = 0.0f;
    gemm_tile<16>(tbuf + (size_t)rowbase * DIM, DIM,
                  wov + (size_t)colbase * DIM, DIM, As, Bs, acc);
    #pragma unroll
    for (int m = 0; m < 4; ++m)
        #pragma unroll
        for (int n = 0; n < 4; ++n)
            #pragma unroll
            for (int rr = 0; rr < 4; ++rr) {
                int orow = rowbase + wr * 64 + m * 16 + ks * 4 + rr;
                int ocol = colbase + wc * 64 + n * 16 + r;
                if (orow < NPTS) {
                    out[(size_t)orow * DIM + ocol] =
                        acc[m][n][rr] + bo[ocol] + features[(size_t)orow * DIM + ocol];
                }
            }
}

// ---------------- FFN1: h = gelu(y @ W1.T + b1), bf16 out, N=1024 --------------------
__global__ __launch_bounds__(256) void ffn1_kernel(
        const short* __restrict__ y, const short* __restrict__ w1,
        const float* __restrict__ b1, short* __restrict__ h) {
    __shared__ short As[128 * 32], Bs[128 * 32];
    int nwg = gridDim.x;             // 782*8
    int bid = blockIdx.x;
    int tile = (bid & 7) * (nwg >> 3) + (bid >> 3);
    int rb = tile >> 3, cb = tile & 7;
    int rowbase = rb * 128, colbase = cb * 128;
    int tid = threadIdx.x;
    int lane = tid & 63, wave = tid >> 6;
    int wr = wave >> 1, wc = wave & 1;
    int r = lane & 15, ks = lane >> 4;
    f32x4 acc[4][4];
    #pragma unroll
    for (int m = 0; m < 4; ++m)
        #pragma unroll
        for (int n = 0; n < 4; ++n)
            #pragma unroll
            for (int e = 0; e < 4; ++e) acc[m][n][e] = 0.0f;
    gemm_tile<16>(y + (size_t)rowbase * DIM, DIM,
                  w1 + (size_t)colbase * DIM, DIM, As, Bs, acc);
    #pragma unroll
    for (int m = 0; m < 4; ++m)
        #pragma unroll
        for (int n = 0; n < 4; ++n)
            #pragma unroll
            for (int rr = 0; rr < 4; ++rr) {
                int orow = rowbase + wr * 64 + m * 16 + ks * 4 + rr;
                int ocol = colbase + wc * 64 + n * 16 + r;
                float xv = acc[m][n][rr] + b1[ocol];
                // exact-GELU via clamped tanh form (max abs err ~3e-3)
                float xc = fminf(fmaxf(xv, -9.0f), 9.0f);
                float u = xc * (0.7978845608028654f + 0.0356774081f * xc * xc);
                float e2 = __expf(2.0f * u);
                float th = (e2 - 1.0f) / (e2 + 1.0f);
                float gl = 0.5f * xv * (1.0f + th);
                h[(size_t)orow * (2 * DIM) + ocol] = f2bf(gl);
            }
}

// ---------------- FFN2: d_out = h @ W2.T + b2 + d_out(res2), K=1024 ------------------
__global__ __launch_bounds__(256) void ffn2_kernel(
        const short* __restrict__ h, const short* __restrict__ w2,
        const float* __restrict__ b2, float* __restrict__ out) {
    __shared__ short As[128 * 32], Bs[128 * 32];
    int nwg = gridDim.x;             // 782*4
    int bid = blockIdx.x;
    int tile = (bid & 7) * (nwg >> 3) + (bid >> 3);
    int rb = tile >> 2, cb = tile & 3;
    int rowbase = rb * 128, colbase = cb * 128;
    int tid = threadIdx.x;
    int lane = tid & 63, wave = tid >> 6;
    int wr = wave >> 1, wc = wave & 1;
    int r = lane & 15, ks = lane >> 4;
    f32x4 acc[4][4];
    #pragma unroll
    for (int m = 0; m < 4; ++m)
        #pragma unroll
        for (int n = 0; n < 4; ++n)
            #pragma unroll
            for (int e = 0; e < 4; ++e) acc[m][n][e] = 0.0f;
    gemm_tile<32>(h + (size_t)rowbase * (2 * DIM), 2 * DIM,
                  w2 + (size_t)colbase * (2 * DIM), 2 * DIM, As, Bs, acc);
    #pragma unroll
    for (int m = 0; m < 4; ++m)
        #pragma unroll
        for (int n = 0; n < 4; ++n)
            #pragma unroll
            for (int rr = 0; rr < 4; ++rr) {
                int orow = rowbase + wr * 64 + m * 16 + ks * 4 + rr;
                int ocol = colbase + wc * 64 + n * 16 + r;
                if (orow < NPTS) {
                    size_t idx = (size_t)orow * DIM + ocol;
                    out[idx] = acc[m][n][rr] + b2[ocol] + out[idx];
                }
            }
}

extern "C" void kernel_launch(void* const* d_in, const int* in_sizes, int n_in,
                              void* d_out, int out_size, void* d_ws, size_t ws_size,
                              hipStream_t stream) {
    const float* features = (const float*)d_in[0];
    const int*   neighbors = (const int*)d_in[2];
    const float* Wq = (const float*)d_in[3];
    const float* Wk = (const float*)d_in[4];
    const float* Wv = (const float*)d_in[5];
    const float* Wo = (const float*)d_in[6];
    const float* bo = (const float*)d_in[7];
    const float* ln1_g = (const float*)d_in[8];
    const float* ln1_b = (const float*)d_in[9];
    const float* ln2_g = (const float*)d_in[10];
    const float* ln2_b = (const float*)d_in[11];
    const float* W1 = (const float*)d_in[12];
    const float* b1 = (const float*)d_in[13];
    const float* W2 = (const float*)d_in[14];
    const float* b2 = (const float*)d_in[15];
    float* out = (float*)d_out;

    size_t slotElems = (size_t)PAD_ROWS * DIM;
    short* s0 = (short*)d_ws;            // x (ln1) -> y (ln2)
    short* s1 = s0 + slotElems;          // q' -> h (low half; s1+s2 contiguous = h[PAD][1024])
    short* s2 = s1 + slotElems;          // t  -> h (high half)
    short* mt_b  = s2 + slotElems;       // 4*128*128
    short* wov_b = mt_b + GRP * GD * GD; // 512*512
    short* w1_b  = wov_b + DIM * DIM;    // 1024*512
    short* w2_b  = w1_b + 2 * DIM * DIM; // 512*1024

    cvt_kernel<<<256, 256, 0, stream>>>(W1, w1_b, 2 * DIM * DIM);
    cvt_kernel<<<256, 256, 0, stream>>>(W2, w2_b, 2 * DIM * DIM);
    prep_m_kernel<<<GRP * GD, GD, 0, stream>>>(Wq, Wk, mt_b);
    prep_wov_kernel<<<DIM, DIM, 0, stream>>>(Wo, Wv, wov_b);

    // LN1: features -> x (bf16), zero-padded rows
    ln_kernel<<<PAD_ROWS, 128, 0, stream>>>(features, ln1_g, ln1_b, s0);

    // q' = Mt x (single grouped GEMM pass)
    qproj_kernel<<<(PAD_ROWS / 128) * 4, 256, 0, stream>>>(s0, mt_b, s1);

    // attention: gather x only -> t in s2
    attn_kernel<<<NPTS, 256, 0, stream>>>(s1, s0, neighbors, s2);

    // out = t @ Wov.T + bo + features  (f32, in d_out)
    outproj_kernel<<<(PAD_ROWS / 128) * 4, 256, 0, stream>>>(s2, wov_b, bo, features, out);

    // LN2: d_out -> y (bf16) in s0
    ln_kernel<<<PAD_ROWS, 128, 0, stream>>>(out, ln2_g, ln2_b, s0);

    // FFN1: h = gelu(y @ W1.T + b1) -> s1..s2 region (PAD x 1024 bf16)
    ffn1_kernel<<<(PAD_ROWS / 128) * 8, 256, 0, stream>>>(s0, w1_b, b1, s1);

    // FFN2: d_out = h @ W2.T + b2 + d_out
    ffn2_kernel<<<(PAD_ROWS / 128) * 4, 256, 0, stream>>>(s1, w2_b, b2, out);
}

// Round 7
// 1125.279 us; speedup vs baseline: 1.3201x; 1.0348x over previous
//
#include <hip/hip_runtime.h>
#include <hip/hip_bf16.h>
#include <math.h>

#define NPTS 100000
#define PAD_ROWS 100096   // 782 * 128
#define DIM 512
#define GRP 4
#define GD 128
#define K_NBR 16
#define EPS 1e-5f

using bf16x8 = __attribute__((ext_vector_type(8))) short;
using f32x4  = __attribute__((ext_vector_type(4))) float;
using short4v = __attribute__((ext_vector_type(4))) short;

__device__ inline float bf2f(short s) {
    unsigned u = ((unsigned)(unsigned short)s) << 16;
    union { unsigned u; float f; } c; c.u = u; return c.f;
}
__device__ inline short f2bf(float f) {
    union { float f; unsigned u; } c; c.f = f;
    unsigned u = c.u;
    unsigned r = (u + 0x7fffu + ((u >> 16) & 1u)) >> 16;
    return (short)r;
}

__device__ __forceinline__ void gload_lds16(short* lds, const short* g) {
    __builtin_amdgcn_global_load_lds(
        (const __attribute__((address_space(1))) unsigned int*)g,
        (__attribute__((address_space(3))) unsigned int*)lds, 16, 0, 0);
}

// ---------------- weight convert f32 -> bf16 ----------------
__global__ void cvt_kernel(const float* __restrict__ src, short* __restrict__ dst, int n) {
    int i = blockIdx.x * blockDim.x + threadIdx.x;
    int stride = gridDim.x * blockDim.x;
    for (; i < n; i += stride) dst[i] = f2bf(src[i]);
}

// ---------------- Mt[g][e][d] = scale * sum_o Wq[g][o][d] * Wk[g][o][e] --------------
__global__ void prep_m_kernel(const float* __restrict__ wq, const float* __restrict__ wk,
                              short* __restrict__ mt) {
    int ge = blockIdx.x;            // g*128 + e
    int g = ge >> 7, e = ge & 127;
    int d = threadIdx.x;            // 128 threads
    const float* Wq = wq + (size_t)g * GD * GD;
    const float* Wk = wk + (size_t)g * GD * GD;
    float acc = 0.0f;
    for (int o = 0; o < GD; ++o)
        acc += Wq[(size_t)o * GD + d] * Wk[(size_t)o * GD + e];
    mt[(size_t)ge * GD + d] = f2bf(acc * 0.08838834764831845f);
}

// ---------------- Wov[o][g*128+i0] = sum_d Wo[o][g*128+d] * Wv[g][d][i0] -------------
__global__ void prep_wov_kernel(const float* __restrict__ wo, const float* __restrict__ wv,
                                short* __restrict__ wov) {
    int o = blockIdx.x;             // 512 blocks
    int i = threadIdx.x;            // 512 threads
    int g = i >> 7, i0 = i & 127;
    float acc = 0.0f;
    for (int d = 0; d < GD; ++d)
        acc += wo[(size_t)o * DIM + g * GD + d] * wv[((size_t)g * GD + d) * GD + i0];
    wov[(size_t)o * DIM + i] = f2bf(acc);
}

// ---------------- LayerNorm (f32 in -> bf16 out) ----------------
__global__ void ln_kernel(const float* __restrict__ in, const float* __restrict__ g,
                          const float* __restrict__ b, short* __restrict__ out) {
    int row = blockIdx.x;
    int tid = threadIdx.x; // 128 threads, 4 elems each
    if (row >= NPTS) {
        short4v z; z[0] = 0; z[1] = 0; z[2] = 0; z[3] = 0;
        *(short4v*)(out + (size_t)row * DIM + tid * 4) = z;
        return;
    }
    const float4 x = *(const float4*)(in + (size_t)row * DIM + tid * 4);
    float s  = x.x + x.y + x.z + x.w;
    float sq = x.x * x.x + x.y * x.y + x.z * x.z + x.w * x.w;
    for (int m = 1; m < 64; m <<= 1) {
        s  += __shfl_xor(s, m);
        sq += __shfl_xor(sq, m);
    }
    __shared__ float ss[2], ssq[2];
    int wv = tid >> 6;
    if ((tid & 63) == 0) { ss[wv] = s; ssq[wv] = sq; }
    __syncthreads();
    s = ss[0] + ss[1]; sq = ssq[0] + ssq[1];
    float mu = s * (1.0f / DIM);
    float var = sq * (1.0f / DIM) - mu * mu;
    float rstd = rsqrtf(var + EPS);
    const float4 gg = *(const float4*)(g + tid * 4);
    const float4 bb = *(const float4*)(b + tid * 4);
    short4v o;
    o[0] = f2bf((x.x - mu) * rstd * gg.x + bb.x);
    o[1] = f2bf((x.y - mu) * rstd * gg.y + bb.y);
    o[2] = f2bf((x.z - mu) * rstd * gg.z + bb.z);
    o[3] = f2bf((x.w - mu) * rstd * gg.w + bb.w);
    *(short4v*)(out + (size_t)row * DIM + tid * 4) = o;
}

// ---------------- 128x128 GEMM core, BK=32, 2-phase double-buffered (T3-minimum) ------
__device__ __forceinline__ void stage_tile(short* As, short* Bs,
        const short* aS, int as_, const short* bS, int bs_, int tid) {
    int ldRow = tid >> 2;            // 0..63
    int ldCol = (tid & 3) * 8;       // element col within BK=32
    gload_lds16(As + (ldRow)      * 32 + ldCol, aS + (size_t)(ldRow)      * as_ + ldCol);
    gload_lds16(As + (ldRow + 64) * 32 + ldCol, aS + (size_t)(ldRow + 64) * as_ + ldCol);
    gload_lds16(Bs + (ldRow)      * 32 + ldCol, bS + (size_t)(ldRow)      * bs_ + ldCol);
    gload_lds16(Bs + (ldRow + 64) * 32 + ldCol, bS + (size_t)(ldRow + 64) * bs_ + ldCol);
}

__device__ __forceinline__ void compute_tile(const short* As, const short* Bs,
        int wr, int wc, int r, int ks, f32x4 (&acc)[4][4]) {
    bf16x8 a[4];
    #pragma unroll
    for (int m = 0; m < 4; ++m)
        a[m] = *(const bf16x8*)(As + (wr * 64 + m * 16 + r) * 32 + ks * 8);
    #pragma unroll
    for (int n = 0; n < 4; ++n) {
        bf16x8 b = *(const bf16x8*)(Bs + (wc * 64 + n * 16 + r) * 32 + ks * 8);
        #pragma unroll
        for (int m = 0; m < 4; ++m)
            acc[m][n] = __builtin_amdgcn_mfma_f32_16x16x32_bf16(a[m], b, acc[m][n], 0, 0, 0);
    }
}

// NK even. Schedule per K-half-step: STAGE(next) -> COMPUTE(cur) -> barrier.
template<int NK>
__device__ __forceinline__ void gemm_tile(
        const short* __restrict__ aBase, int as_,
        const short* __restrict__ bBase, int bs_,
        short* As0, short* Bs0, short* As1, short* Bs1, f32x4 (&acc)[4][4]) {
    int tid = threadIdx.x;
    int lane = tid & 63, wave = tid >> 6;
    int wr = wave >> 1, wc = wave & 1;
    int r = lane & 15, ks = lane >> 4;
    stage_tile(As0, Bs0, aBase, as_, bBase, bs_, tid);
    __syncthreads();
    #pragma unroll
    for (int kt = 0; kt < NK; kt += 2) {
        if (kt + 1 < NK)
            stage_tile(As1, Bs1, aBase + (kt + 1) * 32, as_, bBase + (kt + 1) * 32, bs_, tid);
        compute_tile(As0, Bs0, wr, wc, r, ks, acc);
        __syncthreads();
        if (kt + 2 < NK)
            stage_tile(As0, Bs0, aBase + (kt + 2) * 32, as_, bBase + (kt + 2) * 32, bs_, tid);
        compute_tile(As1, Bs1, wr, wc, r, ks, acc);
        __syncthreads();
    }
}

#define GEMM_LDS \
    __shared__ short As0[128 * 32], Bs0[128 * 32], As1[128 * 32], Bs1[128 * 32]

// ---------------- q' projection: q'[n][g*128+e] = sum_d x[n][g*128+d] * Mt[g][e][d] ---
__global__ __launch_bounds__(256) void qproj_kernel(
        const short* __restrict__ x, const short* __restrict__ mt,
        short* __restrict__ qp) {
    GEMM_LDS;
    int nwg = gridDim.x;             // 782*4 = 3128, %8==0
    int bid = blockIdx.x;
    int tile = (bid & 7) * (nwg >> 3) + (bid >> 3);
    int rb = tile >> 2, g = tile & 3;
    int rowbase = rb * 128;
    int tid = threadIdx.x;
    int lane = tid & 63, wave = tid >> 6;
    int wr = wave >> 1, wc = wave & 1;
    int r = lane & 15, ks = lane >> 4;
    f32x4 acc[4][4];
    #pragma unroll
    for (int m = 0; m < 4; ++m)
        #pragma unroll
        for (int n = 0; n < 4; ++n)
            #pragma unroll
            for (int e = 0; e < 4; ++e) acc[m][n][e] = 0.0f;
    gemm_tile<4>(x + (size_t)rowbase * DIM + g * GD, DIM,
                 mt + (size_t)g * GD * GD, GD, As0, Bs0, As1, Bs1, acc);
    #pragma unroll
    for (int m = 0; m < 4; ++m)
        #pragma unroll
        for (int n = 0; n < 4; ++n)
            #pragma unroll
            for (int rr = 0; rr < 4; ++rr) {
                int orow = rowbase + wr * 64 + m * 16 + ks * 4 + rr;
                int lcol = wc * 64 + n * 16 + r;
                qp[(size_t)orow * DIM + g * GD + lcol] = f2bf(acc[m][n][rr]);
            }
}

// ---------------- attention: gathers x only; t[n][g] = sum_j softmax_j * x_j[g-slice] -
__global__ __launch_bounds__(256) void attn_kernel(
        const short* __restrict__ qp, const short* __restrict__ x,
        const int* __restrict__ nbrs, short* __restrict__ t_out) {
    int b = blockIdx.x;
    int xcd = b & 7;
    int g = xcd >> 1;
    int quad = (b >> 3) * 2 + (xcd & 1);   // 0..24999
    int tid = threadIdx.x;
    int wv = tid >> 6, lane = tid & 63;
    int n = quad * 4 + wv;                 // 0..99999
    int s = lane >> 4, t = lane & 15;
    int4 nbj = *(const int4*)(nbrs + (size_t)n * K_NBR + s * 4);
    int nbarr[4] = {nbj.x, nbj.y, nbj.z, nbj.w};
    size_t goff = (size_t)g * GD + t * 8;
    size_t qbase = (size_t)n * DIM + goff;
    bf16x8 qf = *(const bf16x8*)(qp + qbase);
    float qv[8];
    #pragma unroll
    for (int e = 0; e < 8; ++e) qv[e] = bf2f(qf[e]);
    bf16x8 xf[4];
    #pragma unroll
    for (int p = 0; p < 4; ++p)
        xf[p] = *(const bf16x8*)(x + (size_t)nbarr[p] * DIM + goff);
    float sc[4];
    #pragma unroll
    for (int p = 0; p < 4; ++p) {
        float dd = 0.0f;
        #pragma unroll
        for (int e = 0; e < 8; ++e) dd += qv[e] * bf2f(xf[p][e]);
        dd += __shfl_xor(dd, 1);
        dd += __shfl_xor(dd, 2);
        dd += __shfl_xor(dd, 4);
        dd += __shfl_xor(dd, 8);
        sc[p] = dd;
    }
    float mx = fmaxf(fmaxf(sc[0], sc[1]), fmaxf(sc[2], sc[3]));
    mx = fmaxf(mx, __shfl_xor(mx, 16));
    mx = fmaxf(mx, __shfl_xor(mx, 32));
    float ew[4]; float ssum = 0.0f;
    #pragma unroll
    for (int p = 0; p < 4; ++p) { ew[p] = __expf(sc[p] - mx); ssum += ew[p]; }
    ssum += __shfl_xor(ssum, 16);
    ssum += __shfl_xor(ssum, 32);
    float acc[8];
    #pragma unroll
    for (int d0 = 0; d0 < 8; ++d0) acc[d0] = 0.0f;
    #pragma unroll
    for (int p = 0; p < 4; ++p) {
        #pragma unroll
        for (int d0 = 0; d0 < 8; ++d0) acc[d0] += ew[p] * bf2f(xf[p][d0]);
    }
    #pragma unroll
    for (int d0 = 0; d0 < 8; ++d0) {
        acc[d0] += __shfl_xor(acc[d0], 16);
        acc[d0] += __shfl_xor(acc[d0], 32);
    }
    if (s == 0) {
        float inv = 1.0f / ssum;
        bf16x8 o;
        #pragma unroll
        for (int d0 = 0; d0 < 8; ++d0) o[d0] = f2bf(acc[d0] * inv);
        *(bf16x8*)(t_out + qbase) = o;
    }
}

// ---------------- out = t @ Wov.T + bo + features (residual) -> f32 d_out -------------
__global__ __launch_bounds__(256) void outproj_kernel(
        const short* __restrict__ tbuf, const short* __restrict__ wov,
        const float* __restrict__ bo, const float* __restrict__ features,
        float* __restrict__ out) {
    GEMM_LDS;
    int nwg = gridDim.x;             // 782*4
    int bid = blockIdx.x;
    int tile = (bid & 7) * (nwg >> 3) + (bid >> 3);
    int rb = tile >> 2, cb = tile & 3;
    int rowbase = rb * 128, colbase = cb * 128;
    int tid = threadIdx.x;
    int lane = tid & 63, wave = tid >> 6;
    int wr = wave >> 1, wc = wave & 1;
    int r = lane & 15, ks = lane >> 4;
    f32x4 acc[4][4];
    #pragma unroll
    for (int m = 0; m < 4; ++m)
        #pragma unroll
        for (int n = 0; n < 4; ++n)
            #pragma unroll
            for (int e = 0; e < 4; ++e) acc[m][n][e] = 0.0f;
    gemm_tile<16>(tbuf + (size_t)rowbase * DIM, DIM,
                  wov + (size_t)colbase * DIM, DIM, As0, Bs0, As1, Bs1, acc);
    #pragma unroll
    for (int m = 0; m < 4; ++m)
        #pragma unroll
        for (int n = 0; n < 4; ++n)
            #pragma unroll
            for (int rr = 0; rr < 4; ++rr) {
                int orow = rowbase + wr * 64 + m * 16 + ks * 4 + rr;
                int ocol = colbase + wc * 64 + n * 16 + r;
                if (orow < NPTS) {
                    out[(size_t)orow * DIM + ocol] =
                        acc[m][n][rr] + bo[ocol] + features[(size_t)orow * DIM + ocol];
                }
            }
}

// ---------------- FFN1: h = gelu(y @ W1.T + b1), bf16 out, N=1024 --------------------
__global__ __launch_bounds__(256) void ffn1_kernel(
        const short* __restrict__ y, const short* __restrict__ w1,
        const float* __restrict__ b1, short* __restrict__ h) {
    GEMM_LDS;
    int nwg = gridDim.x;             // 782*8
    int bid = blockIdx.x;
    int tile = (bid & 7) * (nwg >> 3) + (bid >> 3);
    int rb = tile >> 3, cb = tile & 7;
    int rowbase = rb * 128, colbase = cb * 128;
    int tid = threadIdx.x;
    int lane = tid & 63, wave = tid >> 6;
    int wr = wave >> 1, wc = wave & 1;
    int r = lane & 15, ks = lane >> 4;
    f32x4 acc[4][4];
    #pragma unroll
    for (int m = 0; m < 4; ++m)
        #pragma unroll
        for (int n = 0; n < 4; ++n)
            #pragma unroll
            for (int e = 0; e < 4; ++e) acc[m][n][e] = 0.0f;
    gemm_tile<16>(y + (size_t)rowbase * DIM, DIM,
                  w1 + (size_t)colbase * DIM, DIM, As0, Bs0, As1, Bs1, acc);
    #pragma unroll
    for (int m = 0; m < 4; ++m)
        #pragma unroll
        for (int n = 0; n < 4; ++n)
            #pragma unroll
            for (int rr = 0; rr < 4; ++rr) {
                int orow = rowbase + wr * 64 + m * 16 + ks * 4 + rr;
                int ocol = colbase + wc * 64 + n * 16 + r;
                float xv = acc[m][n][rr] + b1[ocol];
                // exact-GELU via clamped tanh form (max abs err ~3e-3)
                float xc = fminf(fmaxf(xv, -9.0f), 9.0f);
                float u = xc * (0.7978845608028654f + 0.0356774081f * xc * xc);
                float e2 = __expf(2.0f * u);
                float th = (e2 - 1.0f) / (e2 + 1.0f);
                float gl = 0.5f * xv * (1.0f + th);
                h[(size_t)orow * (2 * DIM) + ocol] = f2bf(gl);
            }
}

// ---------------- FFN2: d_out = h @ W2.T + b2 + d_out(res2), K=1024 ------------------
__global__ __launch_bounds__(256) void ffn2_kernel(
        const short* __restrict__ h, const short* __restrict__ w2,
        const float* __restrict__ b2, float* __restrict__ out) {
    GEMM_LDS;
    int nwg = gridDim.x;             // 782*4
    int bid = blockIdx.x;
    int tile = (bid & 7) * (nwg >> 3) + (bid >> 3);
    int rb = tile >> 2, cb = tile & 3;
    int rowbase = rb * 128, colbase = cb * 128;
    int tid = threadIdx.x;
    int lane = tid & 63, wave = tid >> 6;
    int wr = wave >> 1, wc = wave & 1;
    int r = lane & 15, ks = lane >> 4;
    f32x4 acc[4][4];
    #pragma unroll
    for (int m = 0; m < 4; ++m)
        #pragma unroll
        for (int n = 0; n < 4; ++n)
            #pragma unroll
            for (int e = 0; e < 4; ++e) acc[m][n][e] = 0.0f;
    gemm_tile<32>(h + (size_t)rowbase * (2 * DIM), 2 * DIM,
                  w2 + (size_t)colbase * (2 * DIM), 2 * DIM, As0, Bs0, As1, Bs1, acc);
    #pragma unroll
    for (int m = 0; m < 4; ++m)
        #pragma unroll
        for (int n = 0; n < 4; ++n)
            #pragma unroll
            for (int rr = 0; rr < 4; ++rr) {
                int orow = rowbase + wr * 64 + m * 16 + ks * 4 + rr;
                int ocol = colbase + wc * 64 + n * 16 + r;
                if (orow < NPTS) {
                    size_t idx = (size_t)orow * DIM + ocol;
                    out[idx] = acc[m][n][rr] + b2[ocol] + out[idx];
                }
            }
}

extern "C" void kernel_launch(void* const* d_in, const int* in_sizes, int n_in,
                              void* d_out, int out_size, void* d_ws, size_t ws_size,
                              hipStream_t stream) {
    const float* features = (const float*)d_in[0];
    const int*   neighbors = (const int*)d_in[2];
    const float* Wq = (const float*)d_in[3];
    const float* Wk = (const float*)d_in[4];
    const float* Wv = (const float*)d_in[5];
    const float* Wo = (const float*)d_in[6];
    const float* bo = (const float*)d_in[7];
    const float* ln1_g = (const float*)d_in[8];
    const float* ln1_b = (const float*)d_in[9];
    const float* ln2_g = (const float*)d_in[10];
    const float* ln2_b = (const float*)d_in[11];
    const float* W1 = (const float*)d_in[12];
    const float* b1 = (const float*)d_in[13];
    const float* W2 = (const float*)d_in[14];
    const float* b2 = (const float*)d_in[15];
    float* out = (float*)d_out;

    size_t slotElems = (size_t)PAD_ROWS * DIM;
    short* s0 = (short*)d_ws;            // x (ln1) -> y (ln2)
    short* s1 = s0 + slotElems;          // q' -> h (low half; s1+s2 contiguous = h[PAD][1024])
    short* s2 = s1 + slotElems;          // t  -> h (high half)
    short* mt_b  = s2 + slotElems;       // 4*128*128
    short* wov_b = mt_b + GRP * GD * GD; // 512*512
    short* w1_b  = wov_b + DIM * DIM;    // 1024*512
    short* w2_b  = w1_b + 2 * DIM * DIM; // 512*1024

    cvt_kernel<<<256, 256, 0, stream>>>(W1, w1_b, 2 * DIM * DIM);
    cvt_kernel<<<256, 256, 0, stream>>>(W2, w2_b, 2 * DIM * DIM);
    prep_m_kernel<<<GRP * GD, GD, 0, stream>>>(Wq, Wk, mt_b);
    prep_wov_kernel<<<DIM, DIM, 0, stream>>>(Wo, Wv, wov_b);

    // LN1: features -> x (bf16), zero-padded rows
    ln_kernel<<<PAD_ROWS, 128, 0, stream>>>(features, ln1_g, ln1_b, s0);

    // q' = Mt x (single grouped GEMM pass)
    qproj_kernel<<<(PAD_ROWS / 128) * 4, 256, 0, stream>>>(s0, mt_b, s1);

    // attention: gather x only -> t in s2
    attn_kernel<<<NPTS, 256, 0, stream>>>(s1, s0, neighbors, s2);

    // out = t @ Wov.T + bo + features  (f32, in d_out)
    outproj_kernel<<<(PAD_ROWS / 128) * 4, 256, 0, stream>>>(s2, wov_b, bo, features, out);

    // LN2: d_out -> y (bf16) in s0
    ln_kernel<<<PAD_ROWS, 128, 0, stream>>>(out, ln2_g, ln2_b, s0);

    // FFN1: h = gelu(y @ W1.T + b1) -> s1..s2 region (PAD x 1024 bf16)
    ffn1_kernel<<<(PAD_ROWS / 128) * 8, 256, 0, stream>>>(s0, w1_b, b1, s1);

    // FFN2: d_out = h @ W2.T + b2 + d_out
    ffn2_kernel<<<(PAD_ROWS / 128) * 4, 256, 0, stream>>>(s1, w2_b, b2, out);
}